// Round 5
// baseline (1350.371 us; speedup 1.0000x reference)
//
#include <hip/hip_runtime.h>

#define NND 100000
#define NE  1600000
#define NF  512
#define NH  64
#define NC  40

#define BROWS 256                          // rows per bucket
#define NB ((NND + BROWS - 1) / BROWS)     // 391 buckets
#define EPB 4096                           // edges per hist/scatter block
#define NEB ((NE + EPB - 1) / EPB)         // 391 blocks

typedef unsigned short u16;
typedef unsigned int   u32;
typedef __attribute__((ext_vector_type(8))) __bf16 bf16x8;
typedef __attribute__((ext_vector_type(4))) float  f32x4;

__device__ __forceinline__ u16 f2bf(float f) {          // f32 -> bf16 RNE
  u32 u = __builtin_bit_cast(u32, f);
  u += 0x7FFFu + ((u >> 16) & 1u);
  return (u16)(u >> 16);
}
__device__ __forceinline__ u32 pack2(float a, float b) {
  return (u32)f2bf(a) | ((u32)f2bf(b) << 16);
}
__device__ __forceinline__ float bf2f(u16 h) {
  return __builtin_bit_cast(float, (u32)h << 16);
}

// ---------------- W1 [512,64] f32 -> W1T [64,512] bf16 ----------------
__global__ __launch_bounds__(256) void w1t_k(const float* __restrict__ W1,
                                             u16* __restrict__ w1t) {
  int i = blockIdx.x * 256 + threadIdx.x;
  if (i >= NF * NH) return;
  int n = i >> 9, k = i & 511;
  w1t[i] = f2bf(W1[(size_t)k * NH + n]);
}

// ---------------- GEMM1 (bf16 MFMA): s1[N,64] = bf16(x[N,512] @ W1) ----------------
__global__ __launch_bounds__(256) void gemm1_k(const float* __restrict__ x,
                                               const u16* __restrict__ w1t,
                                               u16* __restrict__ out) {
  __shared__ u16 As[2][128][72];
  __shared__ u16 Bs[2][64][72];
  const int t = threadIdx.x;
  const int w = t >> 6, lane = t & 63;
  const int l15 = lane & 15, l4 = lane >> 4;
  const int rowBase = blockIdx.x * 128;

  f32x4 acc[2][4];
#pragma unroll
  for (int i = 0; i < 2; ++i)
#pragma unroll
    for (int j = 0; j < 4; ++j) acc[i][j] = (f32x4){0.f, 0.f, 0.f, 0.f};

  float4 aR[4][2];
  uint4  bR[2];

  auto issue = [&](int k0) {
#pragma unroll
    for (int i = 0; i < 4; ++i) {
      int c = t + i * 256;
      int row = rowBase + (c >> 3);
      if (row >= NND) row = NND - 1;
      const float4* s = (const float4*)(x + (size_t)row * NF + k0 + (c & 7) * 8);
      aR[i][0] = s[0];
      aR[i][1] = s[1];
    }
#pragma unroll
    for (int i = 0; i < 2; ++i) {
      int c = t + i * 256;
      bR[i] = *(const uint4*)(w1t + (size_t)(c >> 3) * NF + k0 + (c & 7) * 8);
    }
  };
  auto stage = [&](int b) {
#pragma unroll
    for (int i = 0; i < 4; ++i) {
      int c = t + i * 256;
      uint4 v;
      v.x = pack2(aR[i][0].x, aR[i][0].y);
      v.y = pack2(aR[i][0].z, aR[i][0].w);
      v.z = pack2(aR[i][1].x, aR[i][1].y);
      v.w = pack2(aR[i][1].z, aR[i][1].w);
      *(uint4*)&As[b][c >> 3][(c & 7) * 8] = v;
    }
#pragma unroll
    for (int i = 0; i < 2; ++i) {
      int c = t + i * 256;
      *(uint4*)&Bs[b][c >> 3][(c & 7) * 8] = bR[i];
    }
  };

  issue(0);
  for (int it = 0; it < 8; ++it) {
    const int b = it & 1;
    stage(b);
    if (it < 7) issue((it + 1) * 64);
    __syncthreads();
#pragma unroll
    for (int s = 0; s < 2; ++s) {
      bf16x8 a0 = *(const bf16x8*)&As[b][w * 32 + l15][s * 32 + l4 * 8];
      bf16x8 a1 = *(const bf16x8*)&As[b][w * 32 + 16 + l15][s * 32 + l4 * 8];
#pragma unroll
      for (int ct = 0; ct < 4; ++ct) {
        bf16x8 bb = *(const bf16x8*)&Bs[b][ct * 16 + l15][s * 32 + l4 * 8];
        acc[0][ct] = __builtin_amdgcn_mfma_f32_16x16x32_bf16(a0, bb, acc[0][ct], 0, 0, 0);
        acc[1][ct] = __builtin_amdgcn_mfma_f32_16x16x32_bf16(a1, bb, acc[1][ct], 0, 0, 0);
      }
    }
  }

#pragma unroll
  for (int rt = 0; rt < 2; ++rt)
#pragma unroll
    for (int ct = 0; ct < 4; ++ct)
#pragma unroll
      for (int i = 0; i < 4; ++i) {
        int row = rowBase + w * 32 + rt * 16 + l4 * 4 + i;
        if (row < NND) out[(size_t)row * NH + ct * 16 + l15] = f2bf(acc[rt][ct][i]);
      }
}

// ---------------- bucket histogram (LDS-privatized) ----------------
__global__ __launch_bounds__(1024) void bhist_k(const int* __restrict__ rows,
                                                int* __restrict__ gcount) {
  __shared__ int cnt[NB];
  const int t = threadIdx.x;
  for (int i = t; i < NB; i += 1024) cnt[i] = 0;
  __syncthreads();
  const int base = blockIdx.x * EPB;
#pragma unroll
  for (int k = 0; k < 4; ++k) {
    int i = base + t + k * 1024;
    if (i < NE) atomicAdd(&cnt[rows[i] >> 8], 1);
  }
  __syncthreads();
  for (int i = t; i < NB; i += 1024)
    if (cnt[i]) atomicAdd(&gcount[i], cnt[i]);
}

// ---------------- bucket scan: gcount -> bbase (excl) + gcursor ----------------
__global__ __launch_bounds__(512) void bscan_k(const int* __restrict__ gcount,
                                               int* __restrict__ bbase,
                                               int* __restrict__ gcursor) {
  __shared__ int sh[512];
  const int t = threadIdx.x;
  int v = (t < NB) ? gcount[t] : 0;
  sh[t] = v;
  __syncthreads();
#pragma unroll
  for (int off = 1; off < 512; off <<= 1) {
    int u = (t >= off) ? sh[t - off] : 0;
    __syncthreads();
    sh[t] += u;
    __syncthreads();
  }
  if (t < NB) {
    int ex = sh[t] - v;
    bbase[t] = ex;
    gcursor[t] = ex;
  }
  if (t == 0) bbase[NB] = NE;
}

// ---------------- bucket scatter: block-aggregated positions, run-contiguous writes ----------------
__global__ __launch_bounds__(1024) void bscatter_k(const float* __restrict__ vals,
                                                   const int* __restrict__ rows,
                                                   const int* __restrict__ cols,
                                                   int* __restrict__ gcursor,
                                                   int2* __restrict__ eb) {
  __shared__ int cnt[NB];
  __shared__ int base[NB];
  const int t = threadIdx.x;
  for (int i = t; i < NB; i += 1024) cnt[i] = 0;
  __syncthreads();
  const int gb = blockIdx.x * EPB;
  int bin[4], rnk[4], rr[4], cc[4];
  float vv[4];
#pragma unroll
  for (int k = 0; k < 4; ++k) {
    int i = gb + t + k * 1024;
    if (i < NE) {
      rr[k] = rows[i]; cc[k] = cols[i]; vv[k] = vals[i];
      bin[k] = rr[k] >> 8;
      rnk[k] = atomicAdd(&cnt[bin[k]], 1);
    } else bin[k] = -1;
  }
  __syncthreads();
  for (int i = t; i < NB; i += 1024)
    if (cnt[i]) base[i] = atomicAdd(&gcursor[i], cnt[i]);
  __syncthreads();
#pragma unroll
  for (int k = 0; k < 4; ++k) {
    if (bin[k] >= 0) {
      int pos = base[bin[k]] + rnk[k];
      eb[pos] = make_int2((int)(((u32)cc[k] << 8) | (u32)(rr[k] & 255)),
                          __float_as_int(vv[k]));
    }
  }
}

// ---------------- SpMM1 bucketed: LDS f32 accumulate, fused b1+relu, bf16 out ----------------
__global__ __launch_bounds__(1024) void spmm1b_k(const int* __restrict__ bbase,
                                                 const int2* __restrict__ eb,
                                                 const u16* __restrict__ s1,
                                                 const float* __restrict__ b1,
                                                 u16* __restrict__ h) {
  __shared__ float hacc[BROWS][NH];   // 64 KB
  const int t = threadIdx.x, w = t >> 6, lane = t & 63;
  const int bkt = blockIdx.x;
  for (int i = t; i < BROWS * NH; i += 1024) ((float*)hacc)[i] = 0.f;
  __syncthreads();
  const int beg = bbase[bkt], end = bbase[bkt + 1];
  for (int j0 = beg + w * 64; j0 < end; j0 += 1024) {
    int idx = j0 + lane;
    int2 e = eb[min(idx, end - 1)];
    int n = min(64, end - j0);
    for (int i = 0; i < n; ++i) {
      u32 m   = (u32)__shfl(e.x, i, 64);
      float v = __shfl(__int_as_float(e.y), i, 64);
      int row8 = (int)(m & 255u);
      int col  = (int)(m >> 8);
      float f = bf2f(s1[(size_t)col * NH + lane]);
      atomicAdd(&hacc[row8][lane], v * f);
    }
  }
  __syncthreads();
  for (int r = w; r < BROWS; r += 16) {
    int grow = bkt * BROWS + r;
    if (grow < NND)
      h[(size_t)grow * NH + lane] = f2bf(fmaxf(hacc[r][lane] + b1[lane], 0.f));
  }
}

// ---------------- GEMM2: s2[N,40] = bf16(h_bf16[N,64] @ W10[64,40]) ----------------
__global__ __launch_bounds__(64) void gemm2_k(const u16* __restrict__ h,
                                              const float* __restrict__ W10,
                                              u16* __restrict__ s2out) {
  __shared__ float hs[64][65];
  __shared__ float wl[64][44];
  const int t = threadIdx.x;
  const int rowBase = blockIdx.x * 64;
#pragma unroll
  for (int i = 0; i < 8; ++i) {
    int flat = t + i * 64;             // uint4 index: 8 bf16 each
    int r = flat >> 3, q = flat & 7;
    int row = rowBase + r;
    uint4 v = make_uint4(0, 0, 0, 0);
    if (row < NND) v = *(const uint4*)(h + (size_t)row * NH + q * 8);
    hs[r][q * 8 + 0] = bf2f((u16)(v.x & 0xFFFF));
    hs[r][q * 8 + 1] = bf2f((u16)(v.x >> 16));
    hs[r][q * 8 + 2] = bf2f((u16)(v.y & 0xFFFF));
    hs[r][q * 8 + 3] = bf2f((u16)(v.y >> 16));
    hs[r][q * 8 + 4] = bf2f((u16)(v.z & 0xFFFF));
    hs[r][q * 8 + 5] = bf2f((u16)(v.z >> 16));
    hs[r][q * 8 + 6] = bf2f((u16)(v.w & 0xFFFF));
    hs[r][q * 8 + 7] = bf2f((u16)(v.w >> 16));
  }
#pragma unroll
  for (int i = 0; i < 10; ++i) {
    int flat = t + i * 64;
    int k = flat / 10, c4 = flat - k * 10;
    float4 v = *(const float4*)(W10 + (size_t)flat * 4);
    *(float4*)&wl[k][c4 * 4] = v;
  }
  __syncthreads();

  float4 acc[10] = {};
#pragma unroll 8
  for (int k = 0; k < 64; ++k) {
    float a = hs[t][k];
#pragma unroll
    for (int c = 0; c < 10; ++c) {
      float4 w = *(const float4*)&wl[k][c * 4];
      acc[c].x += a * w.x;
      acc[c].y += a * w.y;
      acc[c].z += a * w.z;
      acc[c].w += a * w.w;
    }
  }
  int row = rowBase + t;
  if (row < NND) {
#pragma unroll
    for (int c = 0; c < 5; ++c) {
      uint4 o;
      o.x = pack2(acc[c * 2].x,     acc[c * 2].y);
      o.y = pack2(acc[c * 2].z,     acc[c * 2].w);
      o.z = pack2(acc[c * 2 + 1].x, acc[c * 2 + 1].y);
      o.w = pack2(acc[c * 2 + 1].z, acc[c * 2 + 1].w);
      *(uint4*)(s2out + (size_t)row * NC + c * 8) = o;
    }
  }
}

// ---------------- SpMM2 bucketed + b10 + fused log_softmax ----------------
__global__ __launch_bounds__(1024) void spmm2b_k(const int* __restrict__ bbase,
                                                 const int2* __restrict__ eb,
                                                 const u16* __restrict__ s2,
                                                 const float* __restrict__ b10,
                                                 float* __restrict__ out) {
  __shared__ float hacc[BROWS][NC];   // 40 KB
  const int t = threadIdx.x, w = t >> 6, lane = t & 63;
  const int bkt = blockIdx.x;
  for (int i = t; i < BROWS * NC; i += 1024) ((float*)hacc)[i] = 0.f;
  __syncthreads();
  const int beg = bbase[bkt], end = bbase[bkt + 1];
  for (int j0 = beg + w * 64; j0 < end; j0 += 1024) {
    int idx = j0 + lane;
    int2 e = eb[min(idx, end - 1)];
    int n = min(64, end - j0);
    for (int i = 0; i < n; ++i) {
      u32 m   = (u32)__shfl(e.x, i, 64);
      float v = __shfl(__int_as_float(e.y), i, 64);
      if (lane < NC) {
        int row8 = (int)(m & 255u);
        int col  = (int)(m >> 8);
        float f = bf2f(s2[(size_t)col * NC + lane]);
        atomicAdd(&hacc[row8][lane], v * f);
      }
    }
  }
  __syncthreads();
  for (int r = w; r < BROWS; r += 16) {
    int grow = bkt * BROWS + r;
    if (grow >= NND) continue;
    float vv = (lane < NC) ? hacc[r][lane] + b10[lane] : -INFINITY;
    float mx = vv;
#pragma unroll
    for (int o = 32; o; o >>= 1) mx = fmaxf(mx, __shfl_xor(mx, o, 64));
    float ee = (lane < NC) ? __expf(vv - mx) : 0.f;
    float ss = ee;
#pragma unroll
    for (int o = 32; o; o >>= 1) ss += __shfl_xor(ss, o, 64);
    if (lane < NC) out[(size_t)grow * NC + lane] = vv - mx - __logf(ss);
  }
}

extern "C" void kernel_launch(void* const* d_in, const int* in_sizes, int n_in,
                              void* d_out, int out_size, void* d_ws, size_t ws_size,
                              hipStream_t stream) {
  const float* x    = (const float*)d_in[0];
  const float* adj  = (const float*)d_in[1];
  const float* W1   = (const float*)d_in[2];
  const float* b1   = (const float*)d_in[3];
  const float* W10  = (const float*)d_in[4];
  const float* b10  = (const float*)d_in[5];
  const int*   erow = (const int*)d_in[6];
  const int*   ecol = (const int*)d_in[7];
  float* out = (float*)d_out;

  char* p = (char*)d_ws;
  u16*  s1  = (u16*)p;    p += (size_t)NND * NH * 2;   // 12.8 MB
  u16*  h   = (u16*)p;    p += (size_t)NND * NH * 2;   // 12.8 MB
  u16*  s2  = (u16*)p;    p += (size_t)NND * NC * 2;   // 8 MB
  u16*  w1t = (u16*)p;    p += (size_t)NF * NH * 2;    // 64 KB
  int2* eb  = (int2*)p;   p += (size_t)NE * 8;         // 12.8 MB
  int* gcount = (int*)p;  p += (size_t)NB * 4;
  int* bbase  = (int*)p;  p += (size_t)(NB + 1) * 4;
  int* gcursor= (int*)p;

  w1t_k<<<(NF * NH + 255) / 256, 256, 0, stream>>>(W1, w1t);

  hipMemsetAsync(gcount, 0, (size_t)NB * sizeof(int), stream);
  bhist_k<<<NEB, 1024, 0, stream>>>(erow, gcount);
  bscan_k<<<1, 512, 0, stream>>>(gcount, bbase, gcursor);
  bscatter_k<<<NEB, 1024, 0, stream>>>(adj, erow, ecol, gcursor, eb);

  gemm1_k<<<(NND + 127) / 128, 256, 0, stream>>>(x, w1t, s1);
  spmm1b_k<<<NB, 1024, 0, stream>>>(bbase, eb, s1, b1, h);
  gemm2_k<<<(NND + 63) / 64, 64, 0, stream>>>(h, W10, s2);
  spmm2b_k<<<NB, 1024, 0, stream>>>(bbase, eb, s2, b10, out);
}

// Round 6
// 268.461 us; speedup vs baseline: 5.0300x; 5.0300x over previous
//
#include <hip/hip_runtime.h>

#define NND 100000
#define NE  1600000
#define NF  512
#define NH  64
#define NC  40

#define BROWS 256                          // rows per bucket
#define NB ((NND + BROWS - 1) / BROWS)     // 391 buckets
#define EPB 4096                           // edges per hist/scatter block
#define NEB ((NE + EPB - 1) / EPB)         // 391 blocks

typedef unsigned short u16;
typedef unsigned int   u32;
typedef __attribute__((ext_vector_type(8))) __bf16 bf16x8;
typedef __attribute__((ext_vector_type(4))) float  f32x4;

__device__ __forceinline__ u16 f2bf(float f) {          // f32 -> bf16 RNE
  u32 u = __builtin_bit_cast(u32, f);
  u += 0x7FFFu + ((u >> 16) & 1u);
  return (u16)(u >> 16);
}
__device__ __forceinline__ u32 pack2(float a, float b) {
  return (u32)f2bf(a) | ((u32)f2bf(b) << 16);
}
__device__ __forceinline__ float bf2f(u16 h) {
  return __builtin_bit_cast(float, (u32)h << 16);
}

// ---------------- W1 [512,64] f32 -> W1T [64,512] bf16 ----------------
__global__ __launch_bounds__(256) void w1t_k(const float* __restrict__ W1,
                                             u16* __restrict__ w1t) {
  int i = blockIdx.x * 256 + threadIdx.x;
  if (i >= NF * NH) return;
  int n = i >> 9, k = i & 511;
  w1t[i] = f2bf(W1[(size_t)k * NH + n]);
}

// ---------------- GEMM1 (bf16 MFMA): s1[N,64] = bf16(x[N,512] @ W1) ----------------
__global__ __launch_bounds__(256) void gemm1_k(const float* __restrict__ x,
                                               const u16* __restrict__ w1t,
                                               u16* __restrict__ out) {
  __shared__ u16 As[2][128][72];
  __shared__ u16 Bs[2][64][72];
  const int t = threadIdx.x;
  const int w = t >> 6, lane = t & 63;
  const int l15 = lane & 15, l4 = lane >> 4;
  const int rowBase = blockIdx.x * 128;

  f32x4 acc[2][4];
#pragma unroll
  for (int i = 0; i < 2; ++i)
#pragma unroll
    for (int j = 0; j < 4; ++j) acc[i][j] = (f32x4){0.f, 0.f, 0.f, 0.f};

  float4 aR[4][2];
  uint4  bR[2];

  auto issue = [&](int k0) {
#pragma unroll
    for (int i = 0; i < 4; ++i) {
      int c = t + i * 256;
      int row = rowBase + (c >> 3);
      if (row >= NND) row = NND - 1;
      const float4* s = (const float4*)(x + (size_t)row * NF + k0 + (c & 7) * 8);
      aR[i][0] = s[0];
      aR[i][1] = s[1];
    }
#pragma unroll
    for (int i = 0; i < 2; ++i) {
      int c = t + i * 256;
      bR[i] = *(const uint4*)(w1t + (size_t)(c >> 3) * NF + k0 + (c & 7) * 8);
    }
  };
  auto stage = [&](int b) {
#pragma unroll
    for (int i = 0; i < 4; ++i) {
      int c = t + i * 256;
      uint4 v;
      v.x = pack2(aR[i][0].x, aR[i][0].y);
      v.y = pack2(aR[i][0].z, aR[i][0].w);
      v.z = pack2(aR[i][1].x, aR[i][1].y);
      v.w = pack2(aR[i][1].z, aR[i][1].w);
      *(uint4*)&As[b][c >> 3][(c & 7) * 8] = v;
    }
#pragma unroll
    for (int i = 0; i < 2; ++i) {
      int c = t + i * 256;
      *(uint4*)&Bs[b][c >> 3][(c & 7) * 8] = bR[i];
    }
  };

  issue(0);
  for (int it = 0; it < 8; ++it) {
    const int b = it & 1;
    stage(b);
    if (it < 7) issue((it + 1) * 64);
    __syncthreads();
#pragma unroll
    for (int s = 0; s < 2; ++s) {
      bf16x8 a0 = *(const bf16x8*)&As[b][w * 32 + l15][s * 32 + l4 * 8];
      bf16x8 a1 = *(const bf16x8*)&As[b][w * 32 + 16 + l15][s * 32 + l4 * 8];
#pragma unroll
      for (int ct = 0; ct < 4; ++ct) {
        bf16x8 bb = *(const bf16x8*)&Bs[b][ct * 16 + l15][s * 32 + l4 * 8];
        acc[0][ct] = __builtin_amdgcn_mfma_f32_16x16x32_bf16(a0, bb, acc[0][ct], 0, 0, 0);
        acc[1][ct] = __builtin_amdgcn_mfma_f32_16x16x32_bf16(a1, bb, acc[1][ct], 0, 0, 0);
      }
    }
  }

#pragma unroll
  for (int rt = 0; rt < 2; ++rt)
#pragma unroll
    for (int ct = 0; ct < 4; ++ct)
#pragma unroll
      for (int i = 0; i < 4; ++i) {
        int row = rowBase + w * 32 + rt * 16 + l4 * 4 + i;
        if (row < NND) out[(size_t)row * NH + ct * 16 + l15] = f2bf(acc[rt][ct][i]);
      }
}

// ---------------- bucket histogram (LDS-privatized) ----------------
__global__ __launch_bounds__(1024) void bhist_k(const int* __restrict__ rows,
                                                int* __restrict__ gcount) {
  __shared__ int cnt[NB];
  const int t = threadIdx.x;
  for (int i = t; i < NB; i += 1024) cnt[i] = 0;
  __syncthreads();
  const int base = blockIdx.x * EPB;
#pragma unroll
  for (int k = 0; k < 4; ++k) {
    int i = base + t + k * 1024;
    if (i < NE) atomicAdd(&cnt[rows[i] >> 8], 1);
  }
  __syncthreads();
  for (int i = t; i < NB; i += 1024)
    if (cnt[i]) atomicAdd(&gcount[i], cnt[i]);
}

// ---------------- bucket scan: gcount -> bbase (excl) + gcursor ----------------
__global__ __launch_bounds__(512) void bscan_k(const int* __restrict__ gcount,
                                               int* __restrict__ bbase,
                                               int* __restrict__ gcursor) {
  __shared__ int sh[512];
  const int t = threadIdx.x;
  int v = (t < NB) ? gcount[t] : 0;
  sh[t] = v;
  __syncthreads();
#pragma unroll
  for (int off = 1; off < 512; off <<= 1) {
    int u = (t >= off) ? sh[t - off] : 0;
    __syncthreads();
    sh[t] += u;
    __syncthreads();
  }
  if (t < NB) {
    int ex = sh[t] - v;
    bbase[t] = ex;
    gcursor[t] = ex;
  }
  if (t == 0) bbase[NB] = NE;
}

// ---------------- bucket scatter: block-aggregated positions, run-contiguous writes ----------------
// eb1 entry: (col<<8 | row&255, val)
__global__ __launch_bounds__(1024) void bscatter_k(const float* __restrict__ vals,
                                                   const int* __restrict__ rows,
                                                   const int* __restrict__ cols,
                                                   int* __restrict__ gcursor,
                                                   int2* __restrict__ eb1) {
  __shared__ int cnt[NB];
  __shared__ int base[NB];
  const int t = threadIdx.x;
  for (int i = t; i < NB; i += 1024) cnt[i] = 0;
  __syncthreads();
  const int gb = blockIdx.x * EPB;
  int bin[4], rnk[4], rr[4], cc[4];
  float vv[4];
#pragma unroll
  for (int k = 0; k < 4; ++k) {
    int i = gb + t + k * 1024;
    if (i < NE) {
      rr[k] = rows[i]; cc[k] = cols[i]; vv[k] = vals[i];
      bin[k] = rr[k] >> 8;
      rnk[k] = atomicAdd(&cnt[bin[k]], 1);
    } else bin[k] = -1;
  }
  __syncthreads();
  for (int i = t; i < NB; i += 1024)
    if (cnt[i]) base[i] = atomicAdd(&gcursor[i], cnt[i]);
  __syncthreads();
#pragma unroll
  for (int k = 0; k < 4; ++k) {
    if (bin[k] >= 0) {
      int pos = base[bin[k]] + rnk[k];
      eb1[pos] = make_int2((int)(((u32)cc[k] << 8) | (u32)(rr[k] & 255)),
                           __float_as_int(vv[k]));
    }
  }
}

// ---------------- per-bucket row sort: eb1 -> eb2 (row-ordered) + exact rowptr ----------------
__global__ __launch_bounds__(1024) void bsort_k(const int* __restrict__ bbase,
                                                const int2* __restrict__ eb1,
                                                int2* __restrict__ eb2,
                                                int* __restrict__ rowptr) {
  __shared__ int cnt[BROWS];
  __shared__ int sc[BROWS];
  const int bkt = blockIdx.x, t = threadIdx.x;
  const int beg = bbase[bkt], end = bbase[bkt + 1];
  if (t < BROWS) cnt[t] = 0;
  __syncthreads();
  int2 mye[6]; int myrow[6]; int myrank[6];
#pragma unroll
  for (int k = 0; k < 6; ++k) {
    int i = beg + t + k * 1024;
    myrow[k] = -1;
    if (i < end) {
      int2 e = eb1[i];
      mye[k] = e;
      myrow[k] = e.x & 255;
      myrank[k] = atomicAdd(&cnt[myrow[k]], 1);   // int LDS atomic: native, fast
    }
  }
  __syncthreads();
  int c0 = (t < BROWS) ? cnt[t] : 0;
  if (t < BROWS) sc[t] = c0;
  __syncthreads();
#pragma unroll
  for (int off = 1; off < BROWS; off <<= 1) {
    int u = (t < BROWS && t >= off) ? sc[t - off] : 0;
    __syncthreads();
    if (t < BROWS) sc[t] += u;
    __syncthreads();
  }
  if (t < BROWS) {
    int ex = sc[t] - c0;                 // exclusive within bucket
    int grow = bkt * BROWS + t;
    if (grow <= NND) rowptr[grow] = beg + ex;
    sc[t] = ex;                          // reuse as row start
  }
  __syncthreads();
#pragma unroll
  for (int k = 0; k < 6; ++k) {
    if (myrow[k] >= 0) {
      int pos = beg + sc[myrow[k]] + myrank[k];
      eb2[pos] = make_int2((int)((u32)mye[k].x >> 8), mye[k].y);  // plain (col, val)
    }
  }
}

// ---------------- SpMM1 gather (bf16 feat): h = bf16(relu(A @ s1 + b1)), wave/row ----------------
__global__ __launch_bounds__(256) void spmm1g_k(const int* __restrict__ rowptr,
                                                const int2* __restrict__ edges,
                                                const u16* __restrict__ feat,
                                                const float* __restrict__ b1,
                                                u16* __restrict__ h) {
  int wid = threadIdx.x >> 6, lane = threadIdx.x & 63;
  int r = blockIdx.x * 4 + wid;
  if (r >= NND) return;
  int beg = rowptr[r], end = rowptr[r + 1];
  float acc0 = 0.f, acc1 = 0.f;
  for (int base = beg; base < end; base += 64) {
    int idx = base + lane;
    int2 e = edges[min(idx, end - 1)];   // coalesced edge load
    int n = min(64, end - base);
    int j = 0;
    for (; j + 1 < n; j += 2) {
      int   c0 = __shfl(e.x, j, 64);
      float v0 = __shfl(__int_as_float(e.y), j, 64);
      int   c1 = __shfl(e.x, j + 1, 64);
      float v1 = __shfl(__int_as_float(e.y), j + 1, 64);
      acc0 = fmaf(v0, bf2f(feat[(size_t)c0 * NH + lane]), acc0);
      acc1 = fmaf(v1, bf2f(feat[(size_t)c1 * NH + lane]), acc1);
    }
    if (j < n) {
      int   c0 = __shfl(e.x, j, 64);
      float v0 = __shfl(__int_as_float(e.y), j, 64);
      acc0 = fmaf(v0, bf2f(feat[(size_t)c0 * NH + lane]), acc0);
    }
  }
  h[(size_t)r * NH + lane] = f2bf(fmaxf(acc0 + acc1 + b1[lane], 0.f));
}

// ---------------- GEMM2: s2[N,40] = bf16(h_bf16[N,64] @ W10[64,40]) ----------------
__global__ __launch_bounds__(64) void gemm2_k(const u16* __restrict__ h,
                                              const float* __restrict__ W10,
                                              u16* __restrict__ s2out) {
  __shared__ float hs[64][65];
  __shared__ float wl[64][44];
  const int t = threadIdx.x;
  const int rowBase = blockIdx.x * 64;
#pragma unroll
  for (int i = 0; i < 8; ++i) {
    int flat = t + i * 64;             // uint4 index: 8 bf16 each
    int r = flat >> 3, q = flat & 7;
    int row = rowBase + r;
    uint4 v = make_uint4(0, 0, 0, 0);
    if (row < NND) v = *(const uint4*)(h + (size_t)row * NH + q * 8);
    hs[r][q * 8 + 0] = bf2f((u16)(v.x & 0xFFFF));
    hs[r][q * 8 + 1] = bf2f((u16)(v.x >> 16));
    hs[r][q * 8 + 2] = bf2f((u16)(v.y & 0xFFFF));
    hs[r][q * 8 + 3] = bf2f((u16)(v.y >> 16));
    hs[r][q * 8 + 4] = bf2f((u16)(v.z & 0xFFFF));
    hs[r][q * 8 + 5] = bf2f((u16)(v.z >> 16));
    hs[r][q * 8 + 6] = bf2f((u16)(v.w & 0xFFFF));
    hs[r][q * 8 + 7] = bf2f((u16)(v.w >> 16));
  }
#pragma unroll
  for (int i = 0; i < 10; ++i) {
    int flat = t + i * 64;
    int k = flat / 10, c4 = flat - k * 10;
    float4 v = *(const float4*)(W10 + (size_t)flat * 4);
    *(float4*)&wl[k][c4 * 4] = v;
  }
  __syncthreads();

  float4 acc[10] = {};
#pragma unroll 8
  for (int k = 0; k < 64; ++k) {
    float a = hs[t][k];
#pragma unroll
    for (int c = 0; c < 10; ++c) {
      float4 w = *(const float4*)&wl[k][c * 4];
      acc[c].x += a * w.x;
      acc[c].y += a * w.y;
      acc[c].z += a * w.z;
      acc[c].w += a * w.w;
    }
  }
  int row = rowBase + t;
  if (row < NND) {
#pragma unroll
    for (int c = 0; c < 5; ++c) {
      uint4 o;
      o.x = pack2(acc[c * 2].x,     acc[c * 2].y);
      o.y = pack2(acc[c * 2].z,     acc[c * 2].w);
      o.z = pack2(acc[c * 2 + 1].x, acc[c * 2 + 1].y);
      o.w = pack2(acc[c * 2 + 1].z, acc[c * 2 + 1].w);
      *(uint4*)(s2out + (size_t)row * NC + c * 8) = o;
    }
  }
}

// ---------------- SpMM2 gather (bf16) + b10 + fused log_softmax, wave/row ----------------
__global__ __launch_bounds__(256) void spmm2g_k(const int* __restrict__ rowptr,
                                                const int2* __restrict__ edges,
                                                const u16* __restrict__ s2,
                                                const float* __restrict__ b10,
                                                float* __restrict__ out) {
  int wid = threadIdx.x >> 6, lane = threadIdx.x & 63;
  int r = blockIdx.x * 4 + wid;
  if (r >= NND) return;
  int beg = rowptr[r], end = rowptr[r + 1];
  int off = (lane < NC) ? lane : 0;
  float acc0 = 0.f, acc1 = 0.f;
  for (int base = beg; base < end; base += 64) {
    int idx = base + lane;
    int2 e = edges[min(idx, end - 1)];
    int n = min(64, end - base);
    int j = 0;
    for (; j + 1 < n; j += 2) {
      int   c0 = __shfl(e.x, j, 64);
      float v0 = __shfl(__int_as_float(e.y), j, 64);
      int   c1 = __shfl(e.x, j + 1, 64);
      float v1 = __shfl(__int_as_float(e.y), j + 1, 64);
      acc0 = fmaf(v0, bf2f(s2[(size_t)c0 * NC + off]), acc0);
      acc1 = fmaf(v1, bf2f(s2[(size_t)c1 * NC + off]), acc1);
    }
    if (j < n) {
      int   c0 = __shfl(e.x, j, 64);
      float v0 = __shfl(__int_as_float(e.y), j, 64);
      acc0 = fmaf(v0, bf2f(s2[(size_t)c0 * NC + off]), acc0);
    }
  }
  float vv = (lane < NC) ? acc0 + acc1 + b10[lane] : -INFINITY;
  float m = vv;
#pragma unroll
  for (int o = 32; o; o >>= 1) m = fmaxf(m, __shfl_xor(m, o, 64));
  float e = (lane < NC) ? __expf(vv - m) : 0.f;
  float s = e;
#pragma unroll
  for (int o = 32; o; o >>= 1) s += __shfl_xor(s, o, 64);
  if (lane < NC) out[(size_t)r * NC + lane] = vv - m - __logf(s);
}

extern "C" void kernel_launch(void* const* d_in, const int* in_sizes, int n_in,
                              void* d_out, int out_size, void* d_ws, size_t ws_size,
                              hipStream_t stream) {
  const float* x    = (const float*)d_in[0];
  const float* adj  = (const float*)d_in[1];
  const float* W1   = (const float*)d_in[2];
  const float* b1   = (const float*)d_in[3];
  const float* W10  = (const float*)d_in[4];
  const float* b10  = (const float*)d_in[5];
  const int*   erow = (const int*)d_in[6];
  const int*   ecol = (const int*)d_in[7];
  float* out = (float*)d_out;

  char* p = (char*)d_ws;
  u16*  s1  = (u16*)p;    p += (size_t)NND * NH * 2;   // 12.8 MB
  u16*  h   = (u16*)p;    p += (size_t)NND * NH * 2;   // 12.8 MB
  u16*  s2  = (u16*)p;    p += (size_t)NND * NC * 2;   // 8 MB
  u16*  w1t = (u16*)p;    p += (size_t)NF * NH * 2;    // 64 KB
  int2* eb1 = (int2*)p;   p += (size_t)NE * 8;         // 12.8 MB
  int2* eb2 = (int2*)p;   p += (size_t)NE * 8;         // 12.8 MB
  int* rowptr = (int*)p;  p += (size_t)(NND + 1) * 4;
  int* gcount = (int*)p;  p += (size_t)NB * 4;
  int* bbase  = (int*)p;  p += (size_t)(NB + 1) * 4;
  int* gcursor= (int*)p;

  w1t_k<<<(NF * NH + 255) / 256, 256, 0, stream>>>(W1, w1t);

  hipMemsetAsync(gcount, 0, (size_t)NB * sizeof(int), stream);
  bhist_k<<<NEB, 1024, 0, stream>>>(erow, gcount);
  bscan_k<<<1, 512, 0, stream>>>(gcount, bbase, gcursor);
  bscatter_k<<<NEB, 1024, 0, stream>>>(adj, erow, ecol, gcursor, eb1);
  bsort_k<<<NB, 1024, 0, stream>>>(bbase, eb1, eb2, rowptr);

  gemm1_k<<<(NND + 127) / 128, 256, 0, stream>>>(x, w1t, s1);
  spmm1g_k<<<(NND + 3) / 4, 256, 0, stream>>>(rowptr, eb2, s1, b1, h);
  gemm2_k<<<(NND + 63) / 64, 64, 0, stream>>>(h, W10, s2);
  spmm2g_k<<<(NND + 3) / 4, 256, 0, stream>>>(rowptr, eb2, s2, b10, out);
}

// Round 7
// 263.952 us; speedup vs baseline: 5.1160x; 1.0171x over previous
//
#include <hip/hip_runtime.h>

#define NND 100000
#define NE  1600000
#define NF  512
#define NH  64
#define NC  40

#define BROWS 256                          // rows per bucket
#define NB ((NND + BROWS - 1) / BROWS)     // 391 buckets
#define EPB 4096                           // edges per hist/scatter block
#define NEB ((NE + EPB - 1) / EPB)         // 391 blocks

typedef unsigned short u16;
typedef unsigned int   u32;
typedef __attribute__((ext_vector_type(8))) __bf16 bf16x8;
typedef __attribute__((ext_vector_type(4))) float  f32x4;

__device__ __forceinline__ u16 f2bf(float f) {          // f32 -> bf16 RNE
  u32 u = __builtin_bit_cast(u32, f);
  u += 0x7FFFu + ((u >> 16) & 1u);
  return (u16)(u >> 16);
}
__device__ __forceinline__ u32 pack2(float a, float b) {
  return (u32)f2bf(a) | ((u32)f2bf(b) << 16);
}
__device__ __forceinline__ float bf2f(u16 h) {
  return __builtin_bit_cast(float, (u32)h << 16);
}

// ---------------- W1 [512,64] f32 -> W1T [64,512] bf16 ; block 0 also zeroes gcount ----------------
__global__ __launch_bounds__(256) void w1t_k(const float* __restrict__ W1,
                                             u16* __restrict__ w1t,
                                             int* __restrict__ gcount) {
  if (blockIdx.x == 0) {
    for (int i = threadIdx.x; i < NB; i += 256) gcount[i] = 0;
  }
  int i = blockIdx.x * 256 + threadIdx.x;
  if (i >= NF * NH) return;
  int n = i >> 9, k = i & 511;
  w1t[i] = f2bf(W1[(size_t)k * NH + n]);
}

// ---------------- GEMM1 (bf16 MFMA): s1[N,64] = bf16(x[N,512] @ W1) ----------------
__global__ __launch_bounds__(256) void gemm1_k(const float* __restrict__ x,
                                               const u16* __restrict__ w1t,
                                               u16* __restrict__ out) {
  __shared__ u16 As[2][128][72];
  __shared__ u16 Bs[2][64][72];
  const int t = threadIdx.x;
  const int w = t >> 6, lane = t & 63;
  const int l15 = lane & 15, l4 = lane >> 4;
  const int rowBase = blockIdx.x * 128;

  f32x4 acc[2][4];
#pragma unroll
  for (int i = 0; i < 2; ++i)
#pragma unroll
    for (int j = 0; j < 4; ++j) acc[i][j] = (f32x4){0.f, 0.f, 0.f, 0.f};

  float4 aR[4][2];
  uint4  bR[2];

  auto issue = [&](int k0) {
#pragma unroll
    for (int i = 0; i < 4; ++i) {
      int c = t + i * 256;
      int row = rowBase + (c >> 3);
      if (row >= NND) row = NND - 1;
      const float4* s = (const float4*)(x + (size_t)row * NF + k0 + (c & 7) * 8);
      aR[i][0] = s[0];
      aR[i][1] = s[1];
    }
#pragma unroll
    for (int i = 0; i < 2; ++i) {
      int c = t + i * 256;
      bR[i] = *(const uint4*)(w1t + (size_t)(c >> 3) * NF + k0 + (c & 7) * 8);
    }
  };
  auto stage = [&](int b) {
#pragma unroll
    for (int i = 0; i < 4; ++i) {
      int c = t + i * 256;
      uint4 v;
      v.x = pack2(aR[i][0].x, aR[i][0].y);
      v.y = pack2(aR[i][0].z, aR[i][0].w);
      v.z = pack2(aR[i][1].x, aR[i][1].y);
      v.w = pack2(aR[i][1].z, aR[i][1].w);
      *(uint4*)&As[b][c >> 3][(c & 7) * 8] = v;
    }
#pragma unroll
    for (int i = 0; i < 2; ++i) {
      int c = t + i * 256;
      *(uint4*)&Bs[b][c >> 3][(c & 7) * 8] = bR[i];
    }
  };

  issue(0);
  for (int it = 0; it < 8; ++it) {
    const int b = it & 1;
    stage(b);
    if (it < 7) issue((it + 1) * 64);
    __syncthreads();
#pragma unroll
    for (int s = 0; s < 2; ++s) {
      bf16x8 a0 = *(const bf16x8*)&As[b][w * 32 + l15][s * 32 + l4 * 8];
      bf16x8 a1 = *(const bf16x8*)&As[b][w * 32 + 16 + l15][s * 32 + l4 * 8];
#pragma unroll
      for (int ct = 0; ct < 4; ++ct) {
        bf16x8 bb = *(const bf16x8*)&Bs[b][ct * 16 + l15][s * 32 + l4 * 8];
        acc[0][ct] = __builtin_amdgcn_mfma_f32_16x16x32_bf16(a0, bb, acc[0][ct], 0, 0, 0);
        acc[1][ct] = __builtin_amdgcn_mfma_f32_16x16x32_bf16(a1, bb, acc[1][ct], 0, 0, 0);
      }
    }
  }

#pragma unroll
  for (int rt = 0; rt < 2; ++rt)
#pragma unroll
    for (int ct = 0; ct < 4; ++ct)
#pragma unroll
      for (int i = 0; i < 4; ++i) {
        int row = rowBase + w * 32 + rt * 16 + l4 * 4 + i;
        if (row < NND) out[(size_t)row * NH + ct * 16 + l15] = f2bf(acc[rt][ct][i]);
      }
}

// ---------------- bucket histogram (LDS-privatized) ----------------
__global__ __launch_bounds__(1024) void bhist_k(const int* __restrict__ rows,
                                                int* __restrict__ gcount) {
  __shared__ int cnt[NB];
  const int t = threadIdx.x;
  for (int i = t; i < NB; i += 1024) cnt[i] = 0;
  __syncthreads();
  const int base = blockIdx.x * EPB;
#pragma unroll
  for (int k = 0; k < 4; ++k) {
    int i = base + t + k * 1024;
    if (i < NE) atomicAdd(&cnt[rows[i] >> 8], 1);
  }
  __syncthreads();
  for (int i = t; i < NB; i += 1024)
    if (cnt[i]) atomicAdd(&gcount[i], cnt[i]);
}

// ---------------- bucket scan: gcount -> bbase (excl) + gcursor ----------------
__global__ __launch_bounds__(512) void bscan_k(const int* __restrict__ gcount,
                                               int* __restrict__ bbase,
                                               int* __restrict__ gcursor) {
  __shared__ int sh[512];
  const int t = threadIdx.x;
  int v = (t < NB) ? gcount[t] : 0;
  sh[t] = v;
  __syncthreads();
#pragma unroll
  for (int off = 1; off < 512; off <<= 1) {
    int u = (t >= off) ? sh[t - off] : 0;
    __syncthreads();
    sh[t] += u;
    __syncthreads();
  }
  if (t < NB) {
    int ex = sh[t] - v;
    bbase[t] = ex;
    gcursor[t] = ex;
  }
  if (t == 0) bbase[NB] = NE;
}

// ---------------- bucket scatter: block-aggregated positions, run-contiguous writes ----------------
// eb1 entry: (col<<8 | row&255, val)
__global__ __launch_bounds__(1024) void bscatter_k(const float* __restrict__ vals,
                                                   const int* __restrict__ rows,
                                                   const int* __restrict__ cols,
                                                   int* __restrict__ gcursor,
                                                   int2* __restrict__ eb1) {
  __shared__ int cnt[NB];
  __shared__ int base[NB];
  const int t = threadIdx.x;
  for (int i = t; i < NB; i += 1024) cnt[i] = 0;
  __syncthreads();
  const int gb = blockIdx.x * EPB;
  int bin[4], rnk[4], rr[4], cc[4];
  float vv[4];
#pragma unroll
  for (int k = 0; k < 4; ++k) {
    int i = gb + t + k * 1024;
    if (i < NE) {
      rr[k] = rows[i]; cc[k] = cols[i]; vv[k] = vals[i];
      bin[k] = rr[k] >> 8;
      rnk[k] = atomicAdd(&cnt[bin[k]], 1);
    } else bin[k] = -1;
  }
  __syncthreads();
  for (int i = t; i < NB; i += 1024)
    if (cnt[i]) base[i] = atomicAdd(&gcursor[i], cnt[i]);
  __syncthreads();
#pragma unroll
  for (int k = 0; k < 4; ++k) {
    if (bin[k] >= 0) {
      int pos = base[bin[k]] + rnk[k];
      eb1[pos] = make_int2((int)(((u32)cc[k] << 8) | (u32)(rr[k] & 255)),
                           __float_as_int(vv[k]));
    }
  }
}

// ---------------- per-bucket row sort: eb1 -> eb2 (row-ordered) + exact rowptr ----------------
__global__ __launch_bounds__(1024) void bsort_k(const int* __restrict__ bbase,
                                                const int2* __restrict__ eb1,
                                                int2* __restrict__ eb2,
                                                int* __restrict__ rowptr) {
  __shared__ int cnt[BROWS];
  __shared__ int sc[BROWS];
  const int bkt = blockIdx.x, t = threadIdx.x;
  const int beg = bbase[bkt], end = bbase[bkt + 1];
  if (t < BROWS) cnt[t] = 0;
  __syncthreads();
  int2 mye[6]; int myrow[6]; int myrank[6];
#pragma unroll
  for (int k = 0; k < 6; ++k) {
    int i = beg + t + k * 1024;
    myrow[k] = -1;
    if (i < end) {
      int2 e = eb1[i];
      mye[k] = e;
      myrow[k] = e.x & 255;
      myrank[k] = atomicAdd(&cnt[myrow[k]], 1);   // int LDS atomic: native, fast
    }
  }
  __syncthreads();
  int c0 = (t < BROWS) ? cnt[t] : 0;
  if (t < BROWS) sc[t] = c0;
  __syncthreads();
#pragma unroll
  for (int off = 1; off < BROWS; off <<= 1) {
    int u = (t < BROWS && t >= off) ? sc[t - off] : 0;
    __syncthreads();
    if (t < BROWS) sc[t] += u;
    __syncthreads();
  }
  if (t < BROWS) {
    int ex = sc[t] - c0;                 // exclusive within bucket
    int grow = bkt * BROWS + t;
    if (grow <= NND) rowptr[grow] = beg + ex;
    sc[t] = ex;                          // reuse as row start
  }
  __syncthreads();
#pragma unroll
  for (int k = 0; k < 6; ++k) {
    if (myrow[k] >= 0) {
      int pos = beg + sc[myrow[k]] + myrank[k];
      eb2[pos] = make_int2((int)((u32)mye[k].x >> 8), mye[k].y);  // plain (col, val)
    }
  }
}

// ---------------- SpMM1 gather (bf16 feat): h = bf16(relu(A @ s1 + b1)), wave/row ----------------
__global__ __launch_bounds__(256) void spmm1g_k(const int* __restrict__ rowptr,
                                                const int2* __restrict__ edges,
                                                const u16* __restrict__ feat,
                                                const float* __restrict__ b1,
                                                u16* __restrict__ h) {
  int wid = threadIdx.x >> 6, lane = threadIdx.x & 63;
  int r = blockIdx.x * 4 + wid;
  if (r >= NND) return;
  int beg = rowptr[r], end = rowptr[r + 1];
  float acc0 = 0.f, acc1 = 0.f;
  for (int base = beg; base < end; base += 64) {
    int idx = base + lane;
    int2 e = edges[min(idx, end - 1)];   // coalesced edge load
    int n = min(64, end - base);
    int j = 0;
    for (; j + 1 < n; j += 2) {
      int   c0 = __shfl(e.x, j, 64);
      float v0 = __shfl(__int_as_float(e.y), j, 64);
      int   c1 = __shfl(e.x, j + 1, 64);
      float v1 = __shfl(__int_as_float(e.y), j + 1, 64);
      acc0 = fmaf(v0, bf2f(feat[(size_t)c0 * NH + lane]), acc0);
      acc1 = fmaf(v1, bf2f(feat[(size_t)c1 * NH + lane]), acc1);
    }
    if (j < n) {
      int   c0 = __shfl(e.x, j, 64);
      float v0 = __shfl(__int_as_float(e.y), j, 64);
      acc0 = fmaf(v0, bf2f(feat[(size_t)c0 * NH + lane]), acc0);
    }
  }
  h[(size_t)r * NH + lane] = f2bf(fmaxf(acc0 + acc1 + b1[lane], 0.f));
}

// ---------------- GEMM2: s2[N,40] = bf16(h_bf16[N,64] @ W10[64,40]) ----------------
__global__ __launch_bounds__(64) void gemm2_k(const u16* __restrict__ h,
                                              const float* __restrict__ W10,
                                              u16* __restrict__ s2out) {
  __shared__ float hs[64][65];
  __shared__ float wl[64][44];
  const int t = threadIdx.x;
  const int rowBase = blockIdx.x * 64;
#pragma unroll
  for (int i = 0; i < 8; ++i) {
    int flat = t + i * 64;             // uint4 index: 8 bf16 each
    int r = flat >> 3, q = flat & 7;
    int row = rowBase + r;
    uint4 v = make_uint4(0, 0, 0, 0);
    if (row < NND) v = *(const uint4*)(h + (size_t)row * NH + q * 8);
    hs[r][q * 8 + 0] = bf2f((u16)(v.x & 0xFFFF));
    hs[r][q * 8 + 1] = bf2f((u16)(v.x >> 16));
    hs[r][q * 8 + 2] = bf2f((u16)(v.y & 0xFFFF));
    hs[r][q * 8 + 3] = bf2f((u16)(v.y >> 16));
    hs[r][q * 8 + 4] = bf2f((u16)(v.z & 0xFFFF));
    hs[r][q * 8 + 5] = bf2f((u16)(v.z >> 16));
    hs[r][q * 8 + 6] = bf2f((u16)(v.w & 0xFFFF));
    hs[r][q * 8 + 7] = bf2f((u16)(v.w >> 16));
  }
#pragma unroll
  for (int i = 0; i < 10; ++i) {
    int flat = t + i * 64;
    int k = flat / 10, c4 = flat - k * 10;
    float4 v = *(const float4*)(W10 + (size_t)flat * 4);
    *(float4*)&wl[k][c4 * 4] = v;
  }
  __syncthreads();

  float4 acc[10] = {};
#pragma unroll 8
  for (int k = 0; k < 64; ++k) {
    float a = hs[t][k];
#pragma unroll
    for (int c = 0; c < 10; ++c) {
      float4 w = *(const float4*)&wl[k][c * 4];
      acc[c].x += a * w.x;
      acc[c].y += a * w.y;
      acc[c].z += a * w.z;
      acc[c].w += a * w.w;
    }
  }
  int row = rowBase + t;
  if (row < NND) {
#pragma unroll
    for (int c = 0; c < 5; ++c) {
      uint4 o;
      o.x = pack2(acc[c * 2].x,     acc[c * 2].y);
      o.y = pack2(acc[c * 2].z,     acc[c * 2].w);
      o.z = pack2(acc[c * 2 + 1].x, acc[c * 2 + 1].y);
      o.w = pack2(acc[c * 2 + 1].z, acc[c * 2 + 1].w);
      *(uint4*)(s2out + (size_t)row * NC + c * 8) = o;
    }
  }
}

// ---------------- SpMM2 gather (bf16) + b10 + fused log_softmax, wave/row ----------------
__global__ __launch_bounds__(256) void spmm2g_k(const int* __restrict__ rowptr,
                                                const int2* __restrict__ edges,
                                                const u16* __restrict__ s2,
                                                const float* __restrict__ b10,
                                                float* __restrict__ out) {
  int wid = threadIdx.x >> 6, lane = threadIdx.x & 63;
  int r = blockIdx.x * 4 + wid;
  if (r >= NND) return;
  int beg = rowptr[r], end = rowptr[r + 1];
  int off = (lane < NC) ? lane : 0;
  float acc0 = 0.f, acc1 = 0.f;
  for (int base = beg; base < end; base += 64) {
    int idx = base + lane;
    int2 e = edges[min(idx, end - 1)];
    int n = min(64, end - base);
    int j = 0;
    for (; j + 1 < n; j += 2) {
      int   c0 = __shfl(e.x, j, 64);
      float v0 = __shfl(__int_as_float(e.y), j, 64);
      int   c1 = __shfl(e.x, j + 1, 64);
      float v1 = __shfl(__int_as_float(e.y), j + 1, 64);
      acc0 = fmaf(v0, bf2f(s2[(size_t)c0 * NC + off]), acc0);
      acc1 = fmaf(v1, bf2f(s2[(size_t)c1 * NC + off]), acc1);
    }
    if (j < n) {
      int   c0 = __shfl(e.x, j, 64);
      float v0 = __shfl(__int_as_float(e.y), j, 64);
      acc0 = fmaf(v0, bf2f(s2[(size_t)c0 * NC + off]), acc0);
    }
  }
  float vv = (lane < NC) ? acc0 + acc1 + b10[lane] : -INFINITY;
  float m = vv;
#pragma unroll
  for (int o = 32; o; o >>= 1) m = fmaxf(m, __shfl_xor(m, o, 64));
  float e = (lane < NC) ? __expf(vv - m) : 0.f;
  float s = e;
#pragma unroll
  for (int o = 32; o; o >>= 1) s += __shfl_xor(s, o, 64);
  if (lane < NC) out[(size_t)r * NC + lane] = vv - m - __logf(s);
}

extern "C" void kernel_launch(void* const* d_in, const int* in_sizes, int n_in,
                              void* d_out, int out_size, void* d_ws, size_t ws_size,
                              hipStream_t stream) {
  const float* x    = (const float*)d_in[0];
  const float* adj  = (const float*)d_in[1];
  const float* W1   = (const float*)d_in[2];
  const float* b1   = (const float*)d_in[3];
  const float* W10  = (const float*)d_in[4];
  const float* b10  = (const float*)d_in[5];
  const int*   erow = (const int*)d_in[6];
  const int*   ecol = (const int*)d_in[7];
  float* out = (float*)d_out;

  char* p = (char*)d_ws;
  u16*  s1  = (u16*)p;    p += (size_t)NND * NH * 2;   // 12.8 MB
  u16*  h   = (u16*)p;    p += (size_t)NND * NH * 2;   // 12.8 MB
  u16*  s2  = (u16*)p;    p += (size_t)NND * NC * 2;   // 8 MB
  u16*  w1t = (u16*)p;    p += (size_t)NF * NH * 2;    // 64 KB
  int2* eb1 = (int2*)p;   p += (size_t)NE * 8;         // 12.8 MB
  int2* eb2 = (int2*)p;   p += (size_t)NE * 8;         // 12.8 MB
  int* rowptr = (int*)p;  p += (size_t)(NND + 1) * 4;
  int* gcount = (int*)p;  p += (size_t)NB * 4;
  int* bbase  = (int*)p;  p += (size_t)(NB + 1) * 4;
  int* gcursor= (int*)p;

  w1t_k<<<(NF * NH + 255) / 256, 256, 0, stream>>>(W1, w1t, gcount);

  bhist_k<<<NEB, 1024, 0, stream>>>(erow, gcount);
  bscan_k<<<1, 512, 0, stream>>>(gcount, bbase, gcursor);
  bscatter_k<<<NEB, 1024, 0, stream>>>(adj, erow, ecol, gcursor, eb1);
  bsort_k<<<NB, 1024, 0, stream>>>(bbase, eb1, eb2, rowptr);

  gemm1_k<<<(NND + 127) / 128, 256, 0, stream>>>(x, w1t, s1);
  spmm1g_k<<<(NND + 3) / 4, 256, 0, stream>>>(rowptr, eb2, s1, b1, h);
  gemm2_k<<<(NND + 63) / 64, 64, 0, stream>>>(h, W10, s2);
  spmm2g_k<<<(NND + 3) / 4, 256, 0, stream>>>(rowptr, eb2, s2, b10, out);
}

// Round 8
// 237.613 us; speedup vs baseline: 5.6831x; 1.1108x over previous
//
#include <hip/hip_runtime.h>

#define NND 100000
#define NE  1600000
#define NF  512
#define NH  64
#define NC  40

#define BROWS 256                          // rows per bucket
#define NB ((NND + BROWS - 1) / BROWS)     // 391 buckets
#define BCAP 4864                          // bucket capacity (mean 4096 + 12 sigma)
#define EPB 4096                           // edges per scatter block
#define NEB ((NE + EPB - 1) / EPB)         // 391 blocks

typedef unsigned short u16;
typedef unsigned int   u32;
typedef __attribute__((ext_vector_type(8))) __bf16 bf16x8;
typedef __attribute__((ext_vector_type(4))) float  f32x4;

__device__ __forceinline__ u16 f2bf(float f) {          // f32 -> bf16 RNE
  u32 u = __builtin_bit_cast(u32, f);
  u += 0x7FFFu + ((u >> 16) & 1u);
  return (u16)(u >> 16);
}
__device__ __forceinline__ u32 pack2(float a, float b) {
  return (u32)f2bf(a) | ((u32)f2bf(b) << 16);
}
__device__ __forceinline__ float bf2f(u16 h) {
  return __builtin_bit_cast(float, (u32)h << 16);
}
__device__ __forceinline__ bf16x8 pack8(const float4& a, const float4& b) {
  uint4 v;
  v.x = pack2(a.x, a.y); v.y = pack2(a.z, a.w);
  v.z = pack2(b.x, b.y); v.w = pack2(b.z, b.w);
  return __builtin_bit_cast(bf16x8, v);
}

// ---------------- W1 [512,64] f32 -> W1T [64,512] bf16 ; block 0 zeroes gcursor ----------------
__global__ __launch_bounds__(256) void w1t_k(const float* __restrict__ W1,
                                             u16* __restrict__ w1t,
                                             int* __restrict__ gcursor) {
  if (blockIdx.x == 0) {
    for (int i = threadIdx.x; i < NB; i += 256) gcursor[i] = 0;
  }
  int i = blockIdx.x * 256 + threadIdx.x;
  if (i >= NF * NH) return;
  int n = i >> 9, k = i & 511;
  w1t[i] = f2bf(W1[(size_t)k * NH + n]);
}

// ---------------- GEMM1 (bf16 MFMA): s1[N,64] = bf16(x[N,512] @ W1) ----------------
// 128 rows x 64 cols per block, BK=64, 4 waves. A-fragments loaded DIRECTLY from
// global (A rows are wave-private -> LDS staging of A is pure overhead);
// only B double-buffered in LDS (18.4 KB).
__global__ __launch_bounds__(256) void gemm1_k(const float* __restrict__ x,
                                               const u16* __restrict__ w1t,
                                               u16* __restrict__ out) {
  __shared__ u16 Bs[2][64][72];
  const int t = threadIdx.x, w = t >> 6, lane = t & 63;
  const int l15 = lane & 15, l4 = lane >> 4;
  const int rowBase = blockIdx.x * 128;
  const int r0 = rowBase + w * 32 + l15;
  const float* pa0 = x + (size_t)min(r0, NND - 1) * NF + l4 * 8;
  const float* pa1 = x + (size_t)min(r0 + 16, NND - 1) * NF + l4 * 8;

  f32x4 acc[2][4];
#pragma unroll
  for (int i = 0; i < 2; ++i)
#pragma unroll
    for (int j = 0; j < 4; ++j) acc[i][j] = (f32x4){0.f, 0.f, 0.f, 0.f};

  uint4  bR[2];
  float4 aR[2][2][2];   // [a0/a1][s][half]

  auto issueB = [&](int k0) {
#pragma unroll
    for (int i = 0; i < 2; ++i) {
      int c = t + i * 256;
      bR[i] = *(const uint4*)(w1t + (size_t)(c >> 3) * NF + k0 + (c & 7) * 8);
    }
  };
  auto issueA = [&](int k0) {
#pragma unroll
    for (int s = 0; s < 2; ++s) {
      const float* q0 = pa0 + k0 + s * 32;
      const float* q1 = pa1 + k0 + s * 32;
      aR[0][s][0] = *(const float4*)(q0);
      aR[0][s][1] = *(const float4*)(q0 + 4);
      aR[1][s][0] = *(const float4*)(q1);
      aR[1][s][1] = *(const float4*)(q1 + 4);
    }
  };

  issueB(0);
  issueA(0);
  for (int it = 0; it < 8; ++it) {
    const int b = it & 1;
#pragma unroll
    for (int i = 0; i < 2; ++i) {          // stage B tile (waits its vmcnt)
      int c = t + i * 256;
      *(uint4*)&Bs[b][c >> 3][(c & 7) * 8] = bR[i];
    }
    bf16x8 fa0[2], fa1[2];                 // pack A frags in registers
#pragma unroll
    for (int s = 0; s < 2; ++s) {
      fa0[s] = pack8(aR[0][s][0], aR[0][s][1]);
      fa1[s] = pack8(aR[1][s][0], aR[1][s][1]);
    }
    if (it < 7) { issueB((it + 1) * 64); issueA((it + 1) * 64); }
    __syncthreads();                       // one barrier per iter (B dbuf)
#pragma unroll
    for (int s = 0; s < 2; ++s) {
#pragma unroll
      for (int ct = 0; ct < 4; ++ct) {
        bf16x8 bb = *(const bf16x8*)&Bs[b][ct * 16 + l15][s * 32 + l4 * 8];
        acc[0][ct] = __builtin_amdgcn_mfma_f32_16x16x32_bf16(fa0[s], bb, acc[0][ct], 0, 0, 0);
        acc[1][ct] = __builtin_amdgcn_mfma_f32_16x16x32_bf16(fa1[s], bb, acc[1][ct], 0, 0, 0);
      }
    }
  }

#pragma unroll
  for (int rt = 0; rt < 2; ++rt)
#pragma unroll
    for (int ct = 0; ct < 4; ++ct)
#pragma unroll
      for (int i = 0; i < 4; ++i) {
        int row = rowBase + w * 32 + rt * 16 + l4 * 4 + i;   // C/D: col=lane&15, row=(lane>>4)*4+reg
        if (row < NND) out[(size_t)row * NH + ct * 16 + l15] = f2bf(acc[rt][ct][i]);
      }
}

// ---------------- bucket scatter (fixed-capacity buckets, bump-allocated) ----------------
// eb1 entry: (col<<8 | row&255, val); bucket b owns eb1[b*BCAP .. b*BCAP+count)
__global__ __launch_bounds__(1024) void bscatter_k(const float* __restrict__ vals,
                                                   const int* __restrict__ rows,
                                                   const int* __restrict__ cols,
                                                   int* __restrict__ gcursor,
                                                   int2* __restrict__ eb1) {
  __shared__ int cnt[NB];
  __shared__ int base[NB];
  const int t = threadIdx.x;
  for (int i = t; i < NB; i += 1024) cnt[i] = 0;
  __syncthreads();
  const int gb = blockIdx.x * EPB;
  int bin[4], rnk[4], rr[4], cc[4];
  float vv[4];
#pragma unroll
  for (int k = 0; k < 4; ++k) {
    int i = gb + t + k * 1024;
    if (i < NE) {
      rr[k] = rows[i]; cc[k] = cols[i]; vv[k] = vals[i];
      bin[k] = rr[k] >> 8;
      rnk[k] = atomicAdd(&cnt[bin[k]], 1);
    } else bin[k] = -1;
  }
  __syncthreads();
  for (int i = t; i < NB; i += 1024)
    if (cnt[i]) base[i] = i * BCAP + atomicAdd(&gcursor[i], cnt[i]);
  __syncthreads();
#pragma unroll
  for (int k = 0; k < 4; ++k) {
    if (bin[k] >= 0) {
      int pos = base[bin[k]] + rnk[k];
      eb1[pos] = make_int2((int)(((u32)cc[k] << 8) | (u32)(rr[k] & 255)),
                           __float_as_int(vv[k]));
    }
  }
}

// ---------------- per-bucket row sort: eb1 -> eb2 (row-ordered) + rowptr/rowcnt ----------------
__global__ __launch_bounds__(1024) void bsort_k(const int* __restrict__ gcursor,
                                                const int2* __restrict__ eb1,
                                                int2* __restrict__ eb2,
                                                int* __restrict__ rowptr,
                                                int* __restrict__ rowcnt) {
  __shared__ int cnt[BROWS];
  __shared__ int sc[BROWS];
  __shared__ int wsum[4];
  const int bkt = blockIdx.x, t = threadIdx.x;
  const int beg = bkt * BCAP;
  const int end = beg + gcursor[bkt];
  if (t < BROWS) cnt[t] = 0;
  __syncthreads();
  int2 mye[6]; int myrow[6]; int myrank[6];
#pragma unroll
  for (int k = 0; k < 6; ++k) {
    int i = beg + t + k * 1024;
    myrow[k] = -1;
    if (i < end) {
      int2 e = eb1[i];
      mye[k] = e;
      myrow[k] = e.x & 255;
      myrank[k] = atomicAdd(&cnt[myrow[k]], 1);   // int LDS atomic: native
    }
  }
  __syncthreads();
  int c0 = 0, inc = 0;
  if (t < BROWS) {
    c0 = cnt[t];
    inc = c0;                                     // per-wave inclusive shfl scan
#pragma unroll
    for (int off = 1; off < 64; off <<= 1) {
      int u = __shfl_up(inc, off, 64);
      if ((t & 63) >= off) inc += u;
    }
    if ((t & 63) == 63) wsum[t >> 6] = inc;
  }
  __syncthreads();
  if (t < BROWS) {
    int wid4 = t >> 6, pre = 0;
#pragma unroll
    for (int k = 0; k < 4; ++k) pre += (k < wid4) ? wsum[k] : 0;
    int ex = pre + inc - c0;                      // exclusive within bucket
    int grow = bkt * BROWS + t;
    if (grow < NND) { rowptr[grow] = beg + ex; rowcnt[grow] = c0; }
    sc[t] = ex;
  }
  __syncthreads();
#pragma unroll
  for (int k = 0; k < 6; ++k) {
    if (myrow[k] >= 0) {
      int pos = beg + sc[myrow[k]] + myrank[k];
      eb2[pos] = make_int2((int)((u32)mye[k].x >> 8), mye[k].y);   // (col, val)
    }
  }
}

// ---------------- SpMM1 gather: h = bf16(relu(A @ s1 + b1)), wave/row, 4-way ILP ----------------
__global__ __launch_bounds__(256) void spmm1g_k(const int* __restrict__ rowptr,
                                                const int* __restrict__ rowcnt,
                                                const int2* __restrict__ edges,
                                                const u16* __restrict__ feat,
                                                const float* __restrict__ b1,
                                                u16* __restrict__ h) {
  int wid = threadIdx.x >> 6, lane = threadIdx.x & 63;
  int r = blockIdx.x * 4 + wid;
  if (r >= NND) return;
  int beg = rowptr[r], end = beg + rowcnt[r];
  float a0 = 0.f, a1 = 0.f, a2 = 0.f, a3 = 0.f;
  for (int base = beg; base < end; base += 64) {
    int2 e = edges[min(base + lane, end - 1)];
    int n = min(64, end - base);
    int j = 0;
    for (; j + 3 < n; j += 4) {
      int   c0 = __shfl(e.x, j, 64);     float v0 = __shfl(__int_as_float(e.y), j, 64);
      int   c1 = __shfl(e.x, j + 1, 64); float v1 = __shfl(__int_as_float(e.y), j + 1, 64);
      int   c2 = __shfl(e.x, j + 2, 64); float v2 = __shfl(__int_as_float(e.y), j + 2, 64);
      int   c3 = __shfl(e.x, j + 3, 64); float v3 = __shfl(__int_as_float(e.y), j + 3, 64);
      a0 = fmaf(v0, bf2f(feat[(size_t)c0 * NH + lane]), a0);
      a1 = fmaf(v1, bf2f(feat[(size_t)c1 * NH + lane]), a1);
      a2 = fmaf(v2, bf2f(feat[(size_t)c2 * NH + lane]), a2);
      a3 = fmaf(v3, bf2f(feat[(size_t)c3 * NH + lane]), a3);
    }
    for (; j < n; ++j) {
      int   c0 = __shfl(e.x, j, 64);
      float v0 = __shfl(__int_as_float(e.y), j, 64);
      a0 = fmaf(v0, bf2f(feat[(size_t)c0 * NH + lane]), a0);
    }
  }
  h[(size_t)r * NH + lane] = f2bf(fmaxf((a0 + a1) + (a2 + a3) + b1[lane], 0.f));
}

// ---------------- GEMM2: s2[N,40] = bf16(h_bf16[N,64] @ W10[64,40]), row/thread ----------------
__global__ __launch_bounds__(256) void gemm2_k(const u16* __restrict__ h,
                                               const float* __restrict__ W10,
                                               u16* __restrict__ s2out) {
  __shared__ float wl[64][44];
  const int t = threadIdx.x;
#pragma unroll
  for (int i = 0; i < 3; ++i) {
    int flat = t + i * 256;
    if (flat < 640) {
      int k = flat / 10, c4 = flat - k * 10;
      *(float4*)&wl[k][c4 * 4] = *(const float4*)(W10 + (size_t)flat * 4);
    }
  }
  __syncthreads();
  int row = blockIdx.x * 256 + t;
  if (row >= NND) return;
  const uint2* hp = (const uint2*)(h + (size_t)row * NH);
  float4 acc[10] = {};
#pragma unroll
  for (int q = 0; q < 16; ++q) {          // 4 bf16 per uint2
    uint2 hv = hp[q];
    float a[4] = {bf2f((u16)(hv.x & 0xFFFF)), bf2f((u16)(hv.x >> 16)),
                  bf2f((u16)(hv.y & 0xFFFF)), bf2f((u16)(hv.y >> 16))};
#pragma unroll
    for (int j = 0; j < 4; ++j) {
      int k = q * 4 + j;
#pragma unroll
      for (int c = 0; c < 10; ++c) {
        float4 wv = *(const float4*)&wl[k][c * 4];
        acc[c].x += a[j] * wv.x;
        acc[c].y += a[j] * wv.y;
        acc[c].z += a[j] * wv.z;
        acc[c].w += a[j] * wv.w;
      }
    }
  }
#pragma unroll
  for (int c = 0; c < 5; ++c) {
    uint4 o;
    o.x = pack2(acc[c * 2].x,     acc[c * 2].y);
    o.y = pack2(acc[c * 2].z,     acc[c * 2].w);
    o.z = pack2(acc[c * 2 + 1].x, acc[c * 2 + 1].y);
    o.w = pack2(acc[c * 2 + 1].z, acc[c * 2 + 1].w);
    *(uint4*)(s2out + (size_t)row * NC + c * 8) = o;
  }
}

// ---------------- SpMM2 gather + b10 + fused log_softmax, wave/row, 4-way ILP ----------------
__global__ __launch_bounds__(256) void spmm2g_k(const int* __restrict__ rowptr,
                                                const int* __restrict__ rowcnt,
                                                const int2* __restrict__ edges,
                                                const u16* __restrict__ s2,
                                                const float* __restrict__ b10,
                                                float* __restrict__ out) {
  int wid = threadIdx.x >> 6, lane = threadIdx.x & 63;
  int r = blockIdx.x * 4 + wid;
  if (r >= NND) return;
  int beg = rowptr[r], end = beg + rowcnt[r];
  int off = (lane < NC) ? lane : 0;
  float a0 = 0.f, a1 = 0.f, a2 = 0.f, a3 = 0.f;
  for (int base = beg; base < end; base += 64) {
    int2 e = edges[min(base + lane, end - 1)];
    int n = min(64, end - base);
    int j = 0;
    for (; j + 3 < n; j += 4) {
      int   c0 = __shfl(e.x, j, 64);     float v0 = __shfl(__int_as_float(e.y), j, 64);
      int   c1 = __shfl(e.x, j + 1, 64); float v1 = __shfl(__int_as_float(e.y), j + 1, 64);
      int   c2 = __shfl(e.x, j + 2, 64); float v2 = __shfl(__int_as_float(e.y), j + 2, 64);
      int   c3 = __shfl(e.x, j + 3, 64); float v3 = __shfl(__int_as_float(e.y), j + 3, 64);
      a0 = fmaf(v0, bf2f(s2[(size_t)c0 * NC + off]), a0);
      a1 = fmaf(v1, bf2f(s2[(size_t)c1 * NC + off]), a1);
      a2 = fmaf(v2, bf2f(s2[(size_t)c2 * NC + off]), a2);
      a3 = fmaf(v3, bf2f(s2[(size_t)c3 * NC + off]), a3);
    }
    for (; j < n; ++j) {
      int   c0 = __shfl(e.x, j, 64);
      float v0 = __shfl(__int_as_float(e.y), j, 64);
      a0 = fmaf(v0, bf2f(s2[(size_t)c0 * NC + off]), a0);
    }
  }
  float vv = (lane < NC) ? (a0 + a1) + (a2 + a3) + b10[lane] : -INFINITY;
  float m = vv;
#pragma unroll
  for (int o = 32; o; o >>= 1) m = fmaxf(m, __shfl_xor(m, o, 64));
  float e = (lane < NC) ? __expf(vv - m) : 0.f;
  float s = e;
#pragma unroll
  for (int o = 32; o; o >>= 1) s += __shfl_xor(s, o, 64);
  if (lane < NC) out[(size_t)r * NC + lane] = vv - m - __logf(s);
}

extern "C" void kernel_launch(void* const* d_in, const int* in_sizes, int n_in,
                              void* d_out, int out_size, void* d_ws, size_t ws_size,
                              hipStream_t stream) {
  const float* x    = (const float*)d_in[0];
  const float* adj  = (const float*)d_in[1];
  const float* W1   = (const float*)d_in[2];
  const float* b1   = (const float*)d_in[3];
  const float* W10  = (const float*)d_in[4];
  const float* b10  = (const float*)d_in[5];
  const int*   erow = (const int*)d_in[6];
  const int*   ecol = (const int*)d_in[7];
  float* out = (float*)d_out;

  char* p = (char*)d_ws;
  u16*  s1  = (u16*)p;    p += (size_t)NND * NH * 2;        // 12.8 MB
  u16*  h   = (u16*)p;    p += (size_t)NND * NH * 2;        // 12.8 MB
  u16*  s2  = (u16*)p;    p += (size_t)NND * NC * 2;        // 8 MB
  u16*  w1t = (u16*)p;    p += (size_t)NF * NH * 2;         // 64 KB
  int2* eb1 = (int2*)p;   p += (size_t)NB * BCAP * 8;       // 15.2 MB
  int2* eb2 = (int2*)p;   p += (size_t)NB * BCAP * 8;       // 15.2 MB
  int* rowptr = (int*)p;  p += (size_t)NND * 4;
  int* rowcnt = (int*)p;  p += (size_t)NND * 4;
  int* gcursor= (int*)p;

  w1t_k<<<(NF * NH + 255) / 256, 256, 0, stream>>>(W1, w1t, gcursor);
  bscatter_k<<<NEB, 1024, 0, stream>>>(adj, erow, ecol, gcursor, eb1);
  bsort_k<<<NB, 1024, 0, stream>>>(gcursor, eb1, eb2, rowptr, rowcnt);

  gemm1_k<<<(NND + 127) / 128, 256, 0, stream>>>(x, w1t, s1);
  spmm1g_k<<<(NND + 3) / 4, 256, 0, stream>>>(rowptr, rowcnt, eb2, s1, b1, h);
  gemm2_k<<<(NND + 255) / 256, 256, 0, stream>>>(h, W10, s2);
  spmm2g_k<<<(NND + 3) / 4, 256, 0, stream>>>(rowptr, rowcnt, eb2, s2, b10, out);
}

// Round 9
// 228.736 us; speedup vs baseline: 5.9036x; 1.0388x over previous
//
#include <hip/hip_runtime.h>

#define NND 100000
#define NE  1600000
#define NF  512
#define NH  64
#define NC  40

#define BROWS 256                          // rows per bucket
#define NB ((NND + BROWS - 1) / BROWS)     // 391 buckets
#define BCAP 4864                          // bucket capacity (mean 4096 + 12 sigma)
#define EPB 4096                           // edges per scatter block
#define NEB ((NE + EPB - 1) / EPB)         // 391 blocks

typedef unsigned short u16;
typedef unsigned int   u32;
typedef __attribute__((ext_vector_type(8))) __bf16 bf16x8;
typedef __attribute__((ext_vector_type(4))) float  f32x4;

__device__ __forceinline__ u16 f2bf(float f) {          // f32 -> bf16 RNE
  u32 u = __builtin_bit_cast(u32, f);
  u += 0x7FFFu + ((u >> 16) & 1u);
  return (u16)(u >> 16);
}
__device__ __forceinline__ u32 pack2(float a, float b) {
  return (u32)f2bf(a) | ((u32)f2bf(b) << 16);
}
__device__ __forceinline__ float bf2f(u16 h) {
  return __builtin_bit_cast(float, (u32)h << 16);
}
__device__ __forceinline__ bf16x8 pack8(const float4& a, const float4& b) {
  uint4 v;
  v.x = pack2(a.x, a.y); v.y = pack2(a.z, a.w);
  v.z = pack2(b.x, b.y); v.w = pack2(b.z, b.w);
  return __builtin_bit_cast(bf16x8, v);
}

// ---------------- W1 [512,64] f32 -> W1T [64,512] bf16 ; block 0 zeroes gcursor ----------------
__global__ __launch_bounds__(256) void w1t_k(const float* __restrict__ W1,
                                             u16* __restrict__ w1t,
                                             int* __restrict__ gcursor) {
  if (blockIdx.x == 0) {
    for (int i = threadIdx.x; i < NB; i += 256) gcursor[i] = 0;
  }
  int i = blockIdx.x * 256 + threadIdx.x;
  if (i >= NF * NH) return;
  int n = i >> 9, k = i & 511;
  w1t[i] = f2bf(W1[(size_t)k * NH + n]);
}

// ---------------- GEMM1 (bf16 MFMA): s1[N,64] = bf16(x[N,512] @ W1) ----------------
// 128 rows x 64 cols per block, BK=64, 4 waves. A direct-from-global (wave-private),
// B double-buffered in LDS.
__global__ __launch_bounds__(256) void gemm1_k(const float* __restrict__ x,
                                               const u16* __restrict__ w1t,
                                               u16* __restrict__ out) {
  __shared__ u16 Bs[2][64][72];
  const int t = threadIdx.x, w = t >> 6, lane = t & 63;
  const int l15 = lane & 15, l4 = lane >> 4;
  const int rowBase = blockIdx.x * 128;
  const int r0 = rowBase + w * 32 + l15;
  const float* pa0 = x + (size_t)min(r0, NND - 1) * NF + l4 * 8;
  const float* pa1 = x + (size_t)min(r0 + 16, NND - 1) * NF + l4 * 8;

  f32x4 acc[2][4];
#pragma unroll
  for (int i = 0; i < 2; ++i)
#pragma unroll
    for (int j = 0; j < 4; ++j) acc[i][j] = (f32x4){0.f, 0.f, 0.f, 0.f};

  uint4  bR[2];
  float4 aR[2][2][2];   // [a0/a1][s][half]

  auto issueB = [&](int k0) {
#pragma unroll
    for (int i = 0; i < 2; ++i) {
      int c = t + i * 256;
      bR[i] = *(const uint4*)(w1t + (size_t)(c >> 3) * NF + k0 + (c & 7) * 8);
    }
  };
  auto issueA = [&](int k0) {
#pragma unroll
    for (int s = 0; s < 2; ++s) {
      const float* q0 = pa0 + k0 + s * 32;
      const float* q1 = pa1 + k0 + s * 32;
      aR[0][s][0] = *(const float4*)(q0);
      aR[0][s][1] = *(const float4*)(q0 + 4);
      aR[1][s][0] = *(const float4*)(q1);
      aR[1][s][1] = *(const float4*)(q1 + 4);
    }
  };

  issueB(0);
  issueA(0);
  for (int it = 0; it < 8; ++it) {
    const int b = it & 1;
#pragma unroll
    for (int i = 0; i < 2; ++i) {          // stage B tile
      int c = t + i * 256;
      *(uint4*)&Bs[b][c >> 3][(c & 7) * 8] = bR[i];
    }
    bf16x8 fa0[2], fa1[2];
#pragma unroll
    for (int s = 0; s < 2; ++s) {
      fa0[s] = pack8(aR[0][s][0], aR[0][s][1]);
      fa1[s] = pack8(aR[1][s][0], aR[1][s][1]);
    }
    if (it < 7) { issueB((it + 1) * 64); issueA((it + 1) * 64); }
    __syncthreads();
#pragma unroll
    for (int s = 0; s < 2; ++s) {
#pragma unroll
      for (int ct = 0; ct < 4; ++ct) {
        bf16x8 bb = *(const bf16x8*)&Bs[b][ct * 16 + l15][s * 32 + l4 * 8];
        acc[0][ct] = __builtin_amdgcn_mfma_f32_16x16x32_bf16(fa0[s], bb, acc[0][ct], 0, 0, 0);
        acc[1][ct] = __builtin_amdgcn_mfma_f32_16x16x32_bf16(fa1[s], bb, acc[1][ct], 0, 0, 0);
      }
    }
  }

#pragma unroll
  for (int rt = 0; rt < 2; ++rt)
#pragma unroll
    for (int ct = 0; ct < 4; ++ct)
#pragma unroll
      for (int i = 0; i < 4; ++i) {
        int row = rowBase + w * 32 + rt * 16 + l4 * 4 + i;   // C/D: col=lane&15, row=(lane>>4)*4+reg
        if (row < NND) out[(size_t)row * NH + ct * 16 + l15] = f2bf(acc[rt][ct][i]);
      }
}

// ---------------- bucket scatter (fixed-capacity buckets, bump-allocated) ----------------
// eb1 entry: (col<<8 | row&255, val); bucket b owns eb1[b*BCAP .. b*BCAP+count)
__global__ __launch_bounds__(1024) void bscatter_k(const float* __restrict__ vals,
                                                   const int* __restrict__ rows,
                                                   const int* __restrict__ cols,
                                                   int* __restrict__ gcursor,
                                                   int2* __restrict__ eb1) {
  __shared__ int cnt[NB];
  __shared__ int base[NB];
  const int t = threadIdx.x;
  for (int i = t; i < NB; i += 1024) cnt[i] = 0;
  __syncthreads();
  const int gb = blockIdx.x * EPB;
  int bin[4], rnk[4], rr[4], cc[4];
  float vv[4];
#pragma unroll
  for (int k = 0; k < 4; ++k) {
    int i = gb + t + k * 1024;
    if (i < NE) {
      rr[k] = rows[i]; cc[k] = cols[i]; vv[k] = vals[i];
      bin[k] = rr[k] >> 8;
      rnk[k] = atomicAdd(&cnt[bin[k]], 1);
    } else bin[k] = -1;
  }
  __syncthreads();
  for (int i = t; i < NB; i += 1024)
    if (cnt[i]) base[i] = i * BCAP + atomicAdd(&gcursor[i], cnt[i]);
  __syncthreads();
#pragma unroll
  for (int k = 0; k < 4; ++k) {
    if (bin[k] >= 0) {
      int pos = base[bin[k]] + rnk[k];
      eb1[pos] = make_int2((int)(((u32)cc[k] << 8) | (u32)(rr[k] & 255)),
                           __float_as_int(vv[k]));
    }
  }
}

// ---------------- SpMM1 fused sort+gather: h = bf16(relu(A @ s1 + b1)) ----------------
// One block per bucket. Sort bucket edges by row in LDS (int atomics + shfl scan),
// then wave w gathers rows w*16..w*16+15 with uniform-LDS edge broadcast.
__global__ __launch_bounds__(1024) void spmm1s_k(const int* __restrict__ gcursor,
                                                 const int2* __restrict__ eb1,
                                                 const u16* __restrict__ s1,
                                                 const float* __restrict__ b1,
                                                 u16* __restrict__ h) {
  __shared__ int2 se[BCAP];          // 38.9 KB sorted edges (col, val)
  __shared__ int cnt[BROWS];
  __shared__ int sc[BROWS];
  __shared__ int wsum[4];
  const int bkt = blockIdx.x, t = threadIdx.x;
  const int w = t >> 6, lane = t & 63;
  const int nE = min(gcursor[bkt], BCAP);
  const int beg = bkt * BCAP;
  if (t < BROWS) cnt[t] = 0;
  __syncthreads();
  int2 mye[5]; int myrow[5], myrank[5];
#pragma unroll
  for (int k = 0; k < 5; ++k) {
    int i = t + k * 1024;
    myrow[k] = -1;
    if (i < nE) {
      int2 e = eb1[beg + i];
      mye[k] = e;
      myrow[k] = e.x & 255;
      myrank[k] = atomicAdd(&cnt[myrow[k]], 1);
    }
  }
  __syncthreads();
  int c0 = 0, inc = 0;
  if (t < BROWS) {
    c0 = cnt[t]; inc = c0;
#pragma unroll
    for (int off = 1; off < 64; off <<= 1) {
      int u = __shfl_up(inc, off, 64);
      if ((t & 63) >= off) inc += u;
    }
    if ((t & 63) == 63) wsum[t >> 6] = inc;
  }
  __syncthreads();
  if (t < BROWS) {
    int pre = 0;
#pragma unroll
    for (int k = 0; k < 4; ++k) pre += (k < (t >> 6)) ? wsum[k] : 0;
    sc[t] = pre + inc - c0;
  }
  __syncthreads();
#pragma unroll
  for (int k = 0; k < 5; ++k)
    if (myrow[k] >= 0)
      se[sc[myrow[k]] + myrank[k]] = make_int2((int)((u32)mye[k].x >> 8), mye[k].y);
  __syncthreads();

  const float bias = b1[lane];
#pragma unroll 1
  for (int i = 0; i < 16; ++i) {
    int r8 = w * 16 + i;
    int s = sc[r8], n = cnt[r8];
    float a0 = 0.f, a1 = 0.f, a2 = 0.f, a3 = 0.f;
    int j = 0;
    for (; j + 3 < n; j += 4) {
      int2 e0 = se[s + j], e1 = se[s + j + 1], e2 = se[s + j + 2], e3 = se[s + j + 3];
      a0 = fmaf(__int_as_float(e0.y), bf2f(s1[(size_t)e0.x * NH + lane]), a0);
      a1 = fmaf(__int_as_float(e1.y), bf2f(s1[(size_t)e1.x * NH + lane]), a1);
      a2 = fmaf(__int_as_float(e2.y), bf2f(s1[(size_t)e2.x * NH + lane]), a2);
      a3 = fmaf(__int_as_float(e3.y), bf2f(s1[(size_t)e3.x * NH + lane]), a3);
    }
    for (; j < n; ++j) {
      int2 e0 = se[s + j];
      a0 = fmaf(__int_as_float(e0.y), bf2f(s1[(size_t)e0.x * NH + lane]), a0);
    }
    int grow = bkt * BROWS + r8;
    if (grow < NND)
      h[(size_t)grow * NH + lane] = f2bf(fmaxf((a0 + a1) + (a2 + a3) + bias, 0.f));
  }
}

// ---------------- GEMM2: s2[N,40] = bf16(h_bf16[N,64] @ W10[64,40]), row/thread ----------------
__global__ __launch_bounds__(256) void gemm2_k(const u16* __restrict__ h,
                                               const float* __restrict__ W10,
                                               u16* __restrict__ s2out) {
  __shared__ float wl[64][44];
  const int t = threadIdx.x;
#pragma unroll
  for (int i = 0; i < 3; ++i) {
    int flat = t + i * 256;
    if (flat < 640) {
      int k = flat / 10, c4 = flat - k * 10;
      *(float4*)&wl[k][c4 * 4] = *(const float4*)(W10 + (size_t)flat * 4);
    }
  }
  __syncthreads();
  int row = blockIdx.x * 256 + t;
  if (row >= NND) return;
  const uint2* hp = (const uint2*)(h + (size_t)row * NH);
  float4 acc[10] = {};
#pragma unroll
  for (int q = 0; q < 16; ++q) {
    uint2 hv = hp[q];
    float a[4] = {bf2f((u16)(hv.x & 0xFFFF)), bf2f((u16)(hv.x >> 16)),
                  bf2f((u16)(hv.y & 0xFFFF)), bf2f((u16)(hv.y >> 16))};
#pragma unroll
    for (int j = 0; j < 4; ++j) {
      int k = q * 4 + j;
#pragma unroll
      for (int c = 0; c < 10; ++c) {
        float4 wv = *(const float4*)&wl[k][c * 4];
        acc[c].x += a[j] * wv.x;
        acc[c].y += a[j] * wv.y;
        acc[c].z += a[j] * wv.z;
        acc[c].w += a[j] * wv.w;
      }
    }
  }
#pragma unroll
  for (int c = 0; c < 5; ++c) {
    uint4 o;
    o.x = pack2(acc[c * 2].x,     acc[c * 2].y);
    o.y = pack2(acc[c * 2].z,     acc[c * 2].w);
    o.z = pack2(acc[c * 2 + 1].x, acc[c * 2 + 1].y);
    o.w = pack2(acc[c * 2 + 1].z, acc[c * 2 + 1].w);
    *(uint4*)(s2out + (size_t)row * NC + c * 8) = o;
  }
}

// ---------------- SpMM2 fused sort+gather + b10 + log_softmax ----------------
__global__ __launch_bounds__(1024) void spmm2s_k(const int* __restrict__ gcursor,
                                                 const int2* __restrict__ eb1,
                                                 const u16* __restrict__ s2,
                                                 const float* __restrict__ b10,
                                                 float* __restrict__ out) {
  __shared__ int2 se[BCAP];
  __shared__ int cnt[BROWS];
  __shared__ int sc[BROWS];
  __shared__ int wsum[4];
  const int bkt = blockIdx.x, t = threadIdx.x;
  const int w = t >> 6, lane = t & 63;
  const int nE = min(gcursor[bkt], BCAP);
  const int beg = bkt * BCAP;
  if (t < BROWS) cnt[t] = 0;
  __syncthreads();
  int2 mye[5]; int myrow[5], myrank[5];
#pragma unroll
  for (int k = 0; k < 5; ++k) {
    int i = t + k * 1024;
    myrow[k] = -1;
    if (i < nE) {
      int2 e = eb1[beg + i];
      mye[k] = e;
      myrow[k] = e.x & 255;
      myrank[k] = atomicAdd(&cnt[myrow[k]], 1);
    }
  }
  __syncthreads();
  int c0 = 0, inc = 0;
  if (t < BROWS) {
    c0 = cnt[t]; inc = c0;
#pragma unroll
    for (int off = 1; off < 64; off <<= 1) {
      int u = __shfl_up(inc, off, 64);
      if ((t & 63) >= off) inc += u;
    }
    if ((t & 63) == 63) wsum[t >> 6] = inc;
  }
  __syncthreads();
  if (t < BROWS) {
    int pre = 0;
#pragma unroll
    for (int k = 0; k < 4; ++k) pre += (k < (t >> 6)) ? wsum[k] : 0;
    sc[t] = pre + inc - c0;
  }
  __syncthreads();
#pragma unroll
  for (int k = 0; k < 5; ++k)
    if (myrow[k] >= 0)
      se[sc[myrow[k]] + myrank[k]] = make_int2((int)((u32)mye[k].x >> 8), mye[k].y);
  __syncthreads();

  const int off0 = (lane < NC) ? lane : 0;
  const float bias = (lane < NC) ? b10[lane] : 0.f;
#pragma unroll 1
  for (int i = 0; i < 16; ++i) {
    int r8 = w * 16 + i;
    int s = cnt[r8] ? sc[r8] : 0;   // cnt first: uniform reads
    int n = cnt[r8];
    float a0 = 0.f, a1 = 0.f, a2 = 0.f, a3 = 0.f;
    int j = 0;
    for (; j + 3 < n; j += 4) {
      int2 e0 = se[s + j], e1 = se[s + j + 1], e2 = se[s + j + 2], e3 = se[s + j + 3];
      a0 = fmaf(__int_as_float(e0.y), bf2f(s2[(size_t)e0.x * NC + off0]), a0);
      a1 = fmaf(__int_as_float(e1.y), bf2f(s2[(size_t)e1.x * NC + off0]), a1);
      a2 = fmaf(__int_as_float(e2.y), bf2f(s2[(size_t)e2.x * NC + off0]), a2);
      a3 = fmaf(__int_as_float(e3.y), bf2f(s2[(size_t)e3.x * NC + off0]), a3);
    }
    for (; j < n; ++j) {
      int2 e0 = se[s + j];
      a0 = fmaf(__int_as_float(e0.y), bf2f(s2[(size_t)e0.x * NC + off0]), a0);
    }
    int grow = bkt * BROWS + r8;
    if (grow >= NND) continue;
    float vv = (lane < NC) ? (a0 + a1) + (a2 + a3) + bias : -INFINITY;
    float m = vv;
#pragma unroll
    for (int o = 32; o; o >>= 1) m = fmaxf(m, __shfl_xor(m, o, 64));
    float e = (lane < NC) ? __expf(vv - m) : 0.f;
    float ss = e;
#pragma unroll
    for (int o = 32; o; o >>= 1) ss += __shfl_xor(ss, o, 64);
    if (lane < NC) out[(size_t)grow * NC + lane] = vv - m - __logf(ss);
  }
}

extern "C" void kernel_launch(void* const* d_in, const int* in_sizes, int n_in,
                              void* d_out, int out_size, void* d_ws, size_t ws_size,
                              hipStream_t stream) {
  const float* x    = (const float*)d_in[0];
  const float* adj  = (const float*)d_in[1];
  const float* W1   = (const float*)d_in[2];
  const float* b1   = (const float*)d_in[3];
  const float* W10  = (const float*)d_in[4];
  const float* b10  = (const float*)d_in[5];
  const int*   erow = (const int*)d_in[6];
  const int*   ecol = (const int*)d_in[7];
  float* out = (float*)d_out;

  char* p = (char*)d_ws;
  u16*  s1  = (u16*)p;    p += (size_t)NND * NH * 2;        // 12.8 MB
  u16*  h   = (u16*)p;    p += (size_t)NND * NH * 2;        // 12.8 MB
  u16*  s2  = (u16*)p;    p += (size_t)NND * NC * 2;        // 8 MB
  u16*  w1t = (u16*)p;    p += (size_t)NF * NH * 2;         // 64 KB
  int2* eb1 = (int2*)p;   p += (size_t)NB * BCAP * 8;       // 15.2 MB
  int* gcursor = (int*)p;

  w1t_k<<<(NF * NH + 255) / 256, 256, 0, stream>>>(W1, w1t, gcursor);
  bscatter_k<<<NEB, 1024, 0, stream>>>(adj, erow, ecol, gcursor, eb1);

  gemm1_k<<<(NND + 127) / 128, 256, 0, stream>>>(x, w1t, s1);
  spmm1s_k<<<NB, 1024, 0, stream>>>(gcursor, eb1, s1, b1, h);
  gemm2_k<<<(NND + 255) / 256, 256, 0, stream>>>(h, W10, s2);
  spmm2s_k<<<NB, 1024, 0, stream>>>(gcursor, eb1, s2, b10, out);
}

// Round 10
// 199.390 us; speedup vs baseline: 6.7725x; 1.1472x over previous
//
#include <hip/hip_runtime.h>

#define NND 100000
#define NE  1600000
#define NF  512
#define NH  64
#define NC  40

#define BROWS 256                          // rows per bucket
#define NB ((NND + BROWS - 1) / BROWS)     // 391 buckets
#define BCAP 4864                          // bucket capacity (mean 4096 + 12 sigma)
#define EPB 4096                           // edges per scatter block
#define NEB ((NE + EPB - 1) / EPB)         // 391 blocks
#define W10PAD 52                          // bf16 LDS pad for W10 (k-stride 26 dwords)
#define HPAD 68                            // bf16 LDS pad for h block (row stride 34 dwords)

typedef unsigned short u16;
typedef unsigned int   u32;
typedef __attribute__((ext_vector_type(8))) __bf16 bf16x8;
typedef __attribute__((ext_vector_type(8))) u16    u16x8;
typedef __attribute__((ext_vector_type(4))) float  f32x4;

__device__ __forceinline__ u16 f2bf(float f) {          // f32 -> bf16 RNE
  u32 u = __builtin_bit_cast(u32, f);
  u += 0x7FFFu + ((u >> 16) & 1u);
  return (u16)(u >> 16);
}
__device__ __forceinline__ u32 pack2(float a, float b) {
  return (u32)f2bf(a) | ((u32)f2bf(b) << 16);
}
__device__ __forceinline__ float bf2f(u16 h) {
  return __builtin_bit_cast(float, (u32)h << 16);
}
__device__ __forceinline__ bf16x8 pack8(const float4& a, const float4& b) {
  uint4 v;
  v.x = pack2(a.x, a.y); v.y = pack2(a.z, a.w);
  v.z = pack2(b.x, b.y); v.w = pack2(b.z, b.w);
  return __builtin_bit_cast(bf16x8, v);
}

// ---------------- W1 [512,64] f32 -> W1T [64,512] bf16 ; block 0 zeroes gcursor ----------------
__global__ __launch_bounds__(256) void w1t_k(const float* __restrict__ W1,
                                             u16* __restrict__ w1t,
                                             int* __restrict__ gcursor) {
  if (blockIdx.x == 0) {
    for (int i = threadIdx.x; i < NB; i += 256) gcursor[i] = 0;
  }
  int i = blockIdx.x * 256 + threadIdx.x;
  if (i >= NF * NH) return;
  int n = i >> 9, k = i & 511;
  w1t[i] = f2bf(W1[(size_t)k * NH + n]);
}

// ---------------- GEMM1 (bf16 MFMA): s1[N,64] = bf16(x[N,512] @ W1) ----------------
// 128 rows x 64 cols per block, BK=64, 4 waves. A direct-from-global (wave-private),
// B double-buffered in LDS.
__global__ __launch_bounds__(256) void gemm1_k(const float* __restrict__ x,
                                               const u16* __restrict__ w1t,
                                               u16* __restrict__ out) {
  __shared__ u16 Bs[2][64][72];
  const int t = threadIdx.x, w = t >> 6, lane = t & 63;
  const int l15 = lane & 15, l4 = lane >> 4;
  const int rowBase = blockIdx.x * 128;
  const int r0 = rowBase + w * 32 + l15;
  const float* pa0 = x + (size_t)min(r0, NND - 1) * NF + l4 * 8;
  const float* pa1 = x + (size_t)min(r0 + 16, NND - 1) * NF + l4 * 8;

  f32x4 acc[2][4];
#pragma unroll
  for (int i = 0; i < 2; ++i)
#pragma unroll
    for (int j = 0; j < 4; ++j) acc[i][j] = (f32x4){0.f, 0.f, 0.f, 0.f};

  uint4  bR[2];
  float4 aR[2][2][2];   // [a0/a1][s][half]

  auto issueB = [&](int k0) {
#pragma unroll
    for (int i = 0; i < 2; ++i) {
      int c = t + i * 256;
      bR[i] = *(const uint4*)(w1t + (size_t)(c >> 3) * NF + k0 + (c & 7) * 8);
    }
  };
  auto issueA = [&](int k0) {
#pragma unroll
    for (int s = 0; s < 2; ++s) {
      const float* q0 = pa0 + k0 + s * 32;
      const float* q1 = pa1 + k0 + s * 32;
      aR[0][s][0] = *(const float4*)(q0);
      aR[0][s][1] = *(const float4*)(q0 + 4);
      aR[1][s][0] = *(const float4*)(q1);
      aR[1][s][1] = *(const float4*)(q1 + 4);
    }
  };

  issueB(0);
  issueA(0);
  for (int it = 0; it < 8; ++it) {
    const int b = it & 1;
#pragma unroll
    for (int i = 0; i < 2; ++i) {          // stage B tile
      int c = t + i * 256;
      *(uint4*)&Bs[b][c >> 3][(c & 7) * 8] = bR[i];
    }
    bf16x8 fa0[2], fa1[2];
#pragma unroll
    for (int s = 0; s < 2; ++s) {
      fa0[s] = pack8(aR[0][s][0], aR[0][s][1]);
      fa1[s] = pack8(aR[1][s][0], aR[1][s][1]);
    }
    if (it < 7) { issueB((it + 1) * 64); issueA((it + 1) * 64); }
    __syncthreads();
#pragma unroll
    for (int s = 0; s < 2; ++s) {
#pragma unroll
      for (int ct = 0; ct < 4; ++ct) {
        bf16x8 bb = *(const bf16x8*)&Bs[b][ct * 16 + l15][s * 32 + l4 * 8];
        acc[0][ct] = __builtin_amdgcn_mfma_f32_16x16x32_bf16(fa0[s], bb, acc[0][ct], 0, 0, 0);
        acc[1][ct] = __builtin_amdgcn_mfma_f32_16x16x32_bf16(fa1[s], bb, acc[1][ct], 0, 0, 0);
      }
    }
  }

#pragma unroll
  for (int rt = 0; rt < 2; ++rt)
#pragma unroll
    for (int ct = 0; ct < 4; ++ct)
#pragma unroll
      for (int i = 0; i < 4; ++i) {
        int row = rowBase + w * 32 + rt * 16 + l4 * 4 + i;   // C/D: col=lane&15, row=(lane>>4)*4+reg
        if (row < NND) out[(size_t)row * NH + ct * 16 + l15] = f2bf(acc[rt][ct][i]);
      }
}

// ---------------- bucket scatter (fixed-capacity buckets, bump-allocated) ----------------
// eb1 entry: (col<<8 | row&255, val); bucket b owns eb1[b*BCAP .. b*BCAP+count)
__global__ __launch_bounds__(1024) void bscatter_k(const float* __restrict__ vals,
                                                   const int* __restrict__ rows,
                                                   const int* __restrict__ cols,
                                                   int* __restrict__ gcursor,
                                                   int2* __restrict__ eb1) {
  __shared__ int cnt[NB];
  __shared__ int base[NB];
  const int t = threadIdx.x;
  for (int i = t; i < NB; i += 1024) cnt[i] = 0;
  __syncthreads();
  const int gb = blockIdx.x * EPB;
  int bin[4], rnk[4], rr[4], cc[4];
  float vv[4];
#pragma unroll
  for (int k = 0; k < 4; ++k) {
    int i = gb + t + k * 1024;
    if (i < NE) {
      rr[k] = rows[i]; cc[k] = cols[i]; vv[k] = vals[i];
      bin[k] = rr[k] >> 8;
      rnk[k] = atomicAdd(&cnt[bin[k]], 1);
    } else bin[k] = -1;
  }
  __syncthreads();
  for (int i = t; i < NB; i += 1024)
    if (cnt[i]) base[i] = i * BCAP + atomicAdd(&gcursor[i], cnt[i]);
  __syncthreads();
#pragma unroll
  for (int k = 0; k < 4; ++k) {
    if (bin[k] >= 0) {
      int pos = base[bin[k]] + rnk[k];
      eb1[pos] = make_int2((int)(((u32)cc[k] << 8) | (u32)(rr[k] & 255)),
                           __float_as_int(vv[k]));
    }
  }
}

// ---------------- SpMM1 fused sort+gather+GEMM2: s2 = bf16(relu(A@s1+b1) @ W10) ----------------
// One block per bucket. Sort bucket edges by row in LDS, gather h rows in registers,
// then per-wave MFMA (h[16x64] @ W10[64x40]) with the se space reused as the h block.
__global__ __launch_bounds__(1024) void spmm1f_k(const int* __restrict__ gcursor,
                                                 const int2* __restrict__ eb1,
                                                 const u16* __restrict__ s1,
                                                 const float* __restrict__ b1,
                                                 const float* __restrict__ W10,
                                                 u16* __restrict__ s2) {
  __shared__ int2 se[BCAP];            // 38.9 KB; reused as per-wave h blocks after gather
  __shared__ u16 w10s[64 * W10PAD];    // 6.7 KB bf16 W10 [k][c], pad 52
  __shared__ int cnt[BROWS];
  __shared__ int sc[BROWS];
  __shared__ int wsum[4];
  const int bkt = blockIdx.x, t = threadIdx.x;
  const int w = t >> 6, lane = t & 63;
  const int nE = min(gcursor[bkt], BCAP);
  const int beg = bkt * BCAP;
  // stage W10 -> bf16 LDS (pad cols zeroed)
  for (int i = t; i < 64 * W10PAD; i += 1024) {
    int k = i / W10PAD, c = i - k * W10PAD;
    w10s[i] = (c < NC) ? f2bf(W10[k * NC + c]) : (u16)0;
  }
  if (t < BROWS) cnt[t] = 0;
  __syncthreads();
  int2 mye[5]; int myrow[5], myrank[5];
#pragma unroll
  for (int k = 0; k < 5; ++k) {
    int i = t + k * 1024;
    myrow[k] = -1;
    if (i < nE) {
      int2 e = eb1[beg + i];
      mye[k] = e;
      myrow[k] = e.x & 255;
      myrank[k] = atomicAdd(&cnt[myrow[k]], 1);
    }
  }
  __syncthreads();
  int c0 = 0, inc = 0;
  if (t < BROWS) {
    c0 = cnt[t]; inc = c0;
#pragma unroll
    for (int off = 1; off < 64; off <<= 1) {
      int u = __shfl_up(inc, off, 64);
      if ((t & 63) >= off) inc += u;
    }
    if ((t & 63) == 63) wsum[t >> 6] = inc;
  }
  __syncthreads();
  if (t < BROWS) {
    int pre = 0;
#pragma unroll
    for (int k = 0; k < 4; ++k) pre += (k < (t >> 6)) ? wsum[k] : 0;
    sc[t] = pre + inc - c0;
  }
  __syncthreads();
#pragma unroll
  for (int k = 0; k < 5; ++k)
    if (myrow[k] >= 0)
      se[sc[myrow[k]] + myrank[k]] = make_int2((int)((u32)mye[k].x >> 8), mye[k].y);
  __syncthreads();

  // gather: wave w owns rows w*16..w*16+15; h kept in registers
  const float bias = b1[lane];
  float hreg[16];
#pragma unroll 1
  for (int i = 0; i < 16; ++i) {
    int r8 = w * 16 + i;
    int s = sc[r8], n = cnt[r8];
    float a0 = 0.f, a1 = 0.f, a2 = 0.f, a3 = 0.f;
    int j = 0;
    for (; j + 3 < n; j += 4) {
      int2 e0 = se[s + j], e1 = se[s + j + 1], e2 = se[s + j + 2], e3 = se[s + j + 3];
      a0 = fmaf(__int_as_float(e0.y), bf2f(s1[(size_t)e0.x * NH + lane]), a0);
      a1 = fmaf(__int_as_float(e1.y), bf2f(s1[(size_t)e1.x * NH + lane]), a1);
      a2 = fmaf(__int_as_float(e2.y), bf2f(s1[(size_t)e2.x * NH + lane]), a2);
      a3 = fmaf(__int_as_float(e3.y), bf2f(s1[(size_t)e3.x * NH + lane]), a3);
    }
    for (; j < n; ++j) {
      int2 e0 = se[s + j];
      a0 = fmaf(__int_as_float(e0.y), bf2f(s1[(size_t)e0.x * NH + lane]), a0);
    }
    hreg[i] = fmaxf((a0 + a1) + (a2 + a3) + bias, 0.f);
  }
  __syncthreads();   // all waves done reading se -> safe to reuse as h blocks

  // write wave-private h block (bf16, pad 68 -> conflict-free b128 A-frag reads)
  u16* hl = (u16*)se + (size_t)w * 16 * HPAD;
#pragma unroll
  for (int i = 0; i < 16; ++i) hl[i * HPAD + lane] = f2bf(hreg[i]);

  const int l15 = lane & 15, l4 = lane >> 4;
  bf16x8 afr[2];   // A-frag: row=l15, k=l4*8 (+32)
  afr[0] = *(const bf16x8*)&hl[l15 * HPAD + l4 * 8];
  afr[1] = *(const bf16x8*)&hl[l15 * HPAD + 32 + l4 * 8];

  f32x4 acc[3];
#pragma unroll
  for (int ct = 0; ct < 3; ++ct) acc[ct] = (f32x4){0.f, 0.f, 0.f, 0.f};
#pragma unroll
  for (int ct = 0; ct < 3; ++ct) {
#pragma unroll
    for (int kk = 0; kk < 2; ++kk) {
      u16x8 bw;
#pragma unroll
      for (int j = 0; j < 8; ++j)
        bw[j] = w10s[(kk * 32 + l4 * 8 + j) * W10PAD + ct * 16 + l15];
      acc[ct] = __builtin_amdgcn_mfma_f32_16x16x32_bf16(
          afr[kk], __builtin_bit_cast(bf16x8, bw), acc[ct], 0, 0, 0);
    }
  }
  // C/D: col=lane&15, row=(lane>>4)*4+reg
#pragma unroll
  for (int ct = 0; ct < 3; ++ct) {
    int c = ct * 16 + l15;
#pragma unroll
    for (int i = 0; i < 4; ++i) {
      int grow = bkt * BROWS + w * 16 + l4 * 4 + i;
      if (c < NC && grow < NND) s2[(size_t)grow * NC + c] = f2bf(acc[ct][i]);
    }
  }
}

// ---------------- SpMM2 fused sort+gather + b10 + log_softmax ----------------
__global__ __launch_bounds__(1024) void spmm2s_k(const int* __restrict__ gcursor,
                                                 const int2* __restrict__ eb1,
                                                 const u16* __restrict__ s2,
                                                 const float* __restrict__ b10,
                                                 float* __restrict__ out) {
  __shared__ int2 se[BCAP];
  __shared__ int cnt[BROWS];
  __shared__ int sc[BROWS];
  __shared__ int wsum[4];
  const int bkt = blockIdx.x, t = threadIdx.x;
  const int w = t >> 6, lane = t & 63;
  const int nE = min(gcursor[bkt], BCAP);
  const int beg = bkt * BCAP;
  if (t < BROWS) cnt[t] = 0;
  __syncthreads();
  int2 mye[5]; int myrow[5], myrank[5];
#pragma unroll
  for (int k = 0; k < 5; ++k) {
    int i = t + k * 1024;
    myrow[k] = -1;
    if (i < nE) {
      int2 e = eb1[beg + i];
      mye[k] = e;
      myrow[k] = e.x & 255;
      myrank[k] = atomicAdd(&cnt[myrow[k]], 1);
    }
  }
  __syncthreads();
  int c0 = 0, inc = 0;
  if (t < BROWS) {
    c0 = cnt[t]; inc = c0;
#pragma unroll
    for (int off = 1; off < 64; off <<= 1) {
      int u = __shfl_up(inc, off, 64);
      if ((t & 63) >= off) inc += u;
    }
    if ((t & 63) == 63) wsum[t >> 6] = inc;
  }
  __syncthreads();
  if (t < BROWS) {
    int pre = 0;
#pragma unroll
    for (int k = 0; k < 4; ++k) pre += (k < (t >> 6)) ? wsum[k] : 0;
    sc[t] = pre + inc - c0;
  }
  __syncthreads();
#pragma unroll
  for (int k = 0; k < 5; ++k)
    if (myrow[k] >= 0)
      se[sc[myrow[k]] + myrank[k]] = make_int2((int)((u32)mye[k].x >> 8), mye[k].y);
  __syncthreads();

  const int off0 = (lane < NC) ? lane : 0;
  const float bias = (lane < NC) ? b10[lane] : 0.f;
#pragma unroll 1
  for (int i = 0; i < 16; ++i) {
    int r8 = w * 16 + i;
    int s = sc[r8], n = cnt[r8];
    float a0 = 0.f, a1 = 0.f, a2 = 0.f, a3 = 0.f;
    int j = 0;
    for (; j + 3 < n; j += 4) {
      int2 e0 = se[s + j], e1 = se[s + j + 1], e2 = se[s + j + 2], e3 = se[s + j + 3];
      a0 = fmaf(__int_as_float(e0.y), bf2f(s2[(size_t)e0.x * NC + off0]), a0);
      a1 = fmaf(__int_as_float(e1.y), bf2f(s2[(size_t)e1.x * NC + off0]), a1);
      a2 = fmaf(__int_as_float(e2.y), bf2f(s2[(size_t)e2.x * NC + off0]), a2);
      a3 = fmaf(__int_as_float(e3.y), bf2f(s2[(size_t)e3.x * NC + off0]), a3);
    }
    for (; j < n; ++j) {
      int2 e0 = se[s + j];
      a0 = fmaf(__int_as_float(e0.y), bf2f(s2[(size_t)e0.x * NC + off0]), a0);
    }
    int grow = bkt * BROWS + r8;
    if (grow >= NND) continue;
    float vv = (lane < NC) ? (a0 + a1) + (a2 + a3) + bias : -INFINITY;
    float m = vv;
#pragma unroll
    for (int o = 32; o; o >>= 1) m = fmaxf(m, __shfl_xor(m, o, 64));
    float e = (lane < NC) ? __expf(vv - m) : 0.f;
    float ss = e;
#pragma unroll
    for (int o = 32; o; o >>= 1) ss += __shfl_xor(ss, o, 64);
    if (lane < NC) out[(size_t)grow * NC + lane] = vv - m - __logf(ss);
  }
}

extern "C" void kernel_launch(void* const* d_in, const int* in_sizes, int n_in,
                              void* d_out, int out_size, void* d_ws, size_t ws_size,
                              hipStream_t stream) {
  const float* x    = (const float*)d_in[0];
  const float* adj  = (const float*)d_in[1];
  const float* W1   = (const float*)d_in[2];
  const float* b1   = (const float*)d_in[3];
  const float* W10  = (const float*)d_in[4];
  const float* b10  = (const float*)d_in[5];
  const int*   erow = (const int*)d_in[6];
  const int*   ecol = (const int*)d_in[7];
  float* out = (float*)d_out;

  char* p = (char*)d_ws;
  u16*  s1  = (u16*)p;    p += (size_t)NND * NH * 2;        // 12.8 MB
  u16*  s2  = (u16*)p;    p += (size_t)NND * NC * 2;        // 8 MB
  u16*  w1t = (u16*)p;    p += (size_t)NF * NH * 2;         // 64 KB
  int2* eb1 = (int2*)p;   p += (size_t)NB * BCAP * 8;       // 15.2 MB
  int* gcursor = (int*)p;

  w1t_k<<<(NF * NH + 255) / 256, 256, 0, stream>>>(W1, w1t, gcursor);
  bscatter_k<<<NEB, 1024, 0, stream>>>(adj, erow, ecol, gcursor, eb1);

  gemm1_k<<<(NND + 127) / 128, 256, 0, stream>>>(x, w1t, s1);
  spmm1f_k<<<NB, 1024, 0, stream>>>(gcursor, eb1, s1, b1, W10, s2);
  spmm2s_k<<<NB, 1024, 0, stream>>>(gcursor, eb1, s2, b10, out);
}

// Round 11
// 198.724 us; speedup vs baseline: 6.7952x; 1.0034x over previous
//
#include <hip/hip_runtime.h>

#define NND 100000
#define NE  1600000
#define NF  512
#define NH  64
#define NC  40

#define BROWS 256                          // rows per bucket
#define NB ((NND + BROWS - 1) / BROWS)     // 391 buckets
#define BCAP 4864                          // bucket capacity (mean 4096 + 12 sigma)
#define EPB 8192                           // edges per scatter block (8/thread)
#define NEB ((NE + EPB - 1) / EPB)         // 196 blocks
#define W10PAD 52                          // bf16 LDS pad for W10
#define HPAD 68                            // bf16 LDS pad for h block

typedef unsigned short u16;
typedef unsigned int   u32;
typedef __attribute__((ext_vector_type(8))) __bf16 bf16x8;
typedef __attribute__((ext_vector_type(8))) u16    u16x8;
typedef __attribute__((ext_vector_type(4))) float  f32x4;

__device__ __forceinline__ u16 f2bf(float f) {          // f32 -> bf16 RNE
  u32 u = __builtin_bit_cast(u32, f);
  u += 0x7FFFu + ((u >> 16) & 1u);
  return (u16)(u >> 16);
}
__device__ __forceinline__ u32 pack2(float a, float b) {
  return (u32)f2bf(a) | ((u32)f2bf(b) << 16);
}
__device__ __forceinline__ float bf2f(u16 h) {
  return __builtin_bit_cast(float, (u32)h << 16);
}
__device__ __forceinline__ bf16x8 pack8(const float4& a, const float4& b) {
  uint4 v;
  v.x = pack2(a.x, a.y); v.y = pack2(a.z, a.w);
  v.z = pack2(b.x, b.y); v.w = pack2(b.z, b.w);
  return __builtin_bit_cast(bf16x8, v);
}

// ---------------- W1 [512,64] f32 -> W1T [64,512] bf16 ; block 0 zeroes gcursor ----------------
__global__ __launch_bounds__(256) void w1t_k(const float* __restrict__ W1,
                                             u16* __restrict__ w1t,
                                             int* __restrict__ gcursor) {
  if (blockIdx.x == 0) {
    for (int i = threadIdx.x; i < NB; i += 256) gcursor[i] = 0;
  }
  int i = blockIdx.x * 256 + threadIdx.x;
  if (i >= NF * NH) return;
  int n = i >> 9, k = i & 511;
  w1t[i] = f2bf(W1[(size_t)k * NH + n]);
}

// ---------------- GEMM1 (bf16 MFMA): s1[N,64] = bf16(x[N,512] @ W1) ----------------
__global__ __launch_bounds__(256) void gemm1_k(const float* __restrict__ x,
                                               const u16* __restrict__ w1t,
                                               u16* __restrict__ out) {
  __shared__ u16 Bs[2][64][72];
  const int t = threadIdx.x, w = t >> 6, lane = t & 63;
  const int l15 = lane & 15, l4 = lane >> 4;
  const int rowBase = blockIdx.x * 128;
  const int r0 = rowBase + w * 32 + l15;
  const float* pa0 = x + (size_t)min(r0, NND - 1) * NF + l4 * 8;
  const float* pa1 = x + (size_t)min(r0 + 16, NND - 1) * NF + l4 * 8;

  f32x4 acc[2][4];
#pragma unroll
  for (int i = 0; i < 2; ++i)
#pragma unroll
    for (int j = 0; j < 4; ++j) acc[i][j] = (f32x4){0.f, 0.f, 0.f, 0.f};

  uint4  bR[2];
  float4 aR[2][2][2];   // [a0/a1][s][half]

  auto issueB = [&](int k0) {
#pragma unroll
    for (int i = 0; i < 2; ++i) {
      int c = t + i * 256;
      bR[i] = *(const uint4*)(w1t + (size_t)(c >> 3) * NF + k0 + (c & 7) * 8);
    }
  };
  auto issueA = [&](int k0) {
#pragma unroll
    for (int s = 0; s < 2; ++s) {
      const float* q0 = pa0 + k0 + s * 32;
      const float* q1 = pa1 + k0 + s * 32;
      aR[0][s][0] = *(const float4*)(q0);
      aR[0][s][1] = *(const float4*)(q0 + 4);
      aR[1][s][0] = *(const float4*)(q1);
      aR[1][s][1] = *(const float4*)(q1 + 4);
    }
  };

  issueB(0);
  issueA(0);
  for (int it = 0; it < 8; ++it) {
    const int b = it & 1;
#pragma unroll
    for (int i = 0; i < 2; ++i) {          // stage B tile
      int c = t + i * 256;
      *(uint4*)&Bs[b][c >> 3][(c & 7) * 8] = bR[i];
    }
    bf16x8 fa0[2], fa1[2];
#pragma unroll
    for (int s = 0; s < 2; ++s) {
      fa0[s] = pack8(aR[0][s][0], aR[0][s][1]);
      fa1[s] = pack8(aR[1][s][0], aR[1][s][1]);
    }
    if (it < 7) { issueB((it + 1) * 64); issueA((it + 1) * 64); }
    __syncthreads();
#pragma unroll
    for (int s = 0; s < 2; ++s) {
#pragma unroll
      for (int ct = 0; ct < 4; ++ct) {
        bf16x8 bb = *(const bf16x8*)&Bs[b][ct * 16 + l15][s * 32 + l4 * 8];
        acc[0][ct] = __builtin_amdgcn_mfma_f32_16x16x32_bf16(fa0[s], bb, acc[0][ct], 0, 0, 0);
        acc[1][ct] = __builtin_amdgcn_mfma_f32_16x16x32_bf16(fa1[s], bb, acc[1][ct], 0, 0, 0);
      }
    }
  }

#pragma unroll
  for (int rt = 0; rt < 2; ++rt)
#pragma unroll
    for (int ct = 0; ct < 4; ++ct)
#pragma unroll
      for (int i = 0; i < 4; ++i) {
        int row = rowBase + w * 32 + rt * 16 + l4 * 4 + i;   // C/D: col=lane&15, row=(lane>>4)*4+reg
        if (row < NND) out[(size_t)row * NH + ct * 16 + l15] = f2bf(acc[rt][ct][i]);
      }
}

// ---------------- bucket scatter (fixed-capacity buckets, bump-allocated) ----------------
// eb1 entry: (col<<8 | row&255, val); bucket b owns eb1[b*BCAP .. b*BCAP+count)
__global__ __launch_bounds__(1024) void bscatter_k(const float* __restrict__ vals,
                                                   const int* __restrict__ rows,
                                                   const int* __restrict__ cols,
                                                   int* __restrict__ gcursor,
                                                   int2* __restrict__ eb1) {
  __shared__ int cnt[NB];
  __shared__ int base[NB];
  const int t = threadIdx.x;
  for (int i = t; i < NB; i += 1024) cnt[i] = 0;
  __syncthreads();
  const int gb = blockIdx.x * EPB;
  int bin[8], rnk[8], rr[8], cc[8];
  float vv[8];
#pragma unroll
  for (int k = 0; k < 8; ++k) {
    int i = gb + t + k * 1024;
    if (i < NE) {
      rr[k] = rows[i]; cc[k] = cols[i]; vv[k] = vals[i];
      bin[k] = rr[k] >> 8;
      rnk[k] = atomicAdd(&cnt[bin[k]], 1);
    } else bin[k] = -1;
  }
  __syncthreads();
  for (int i = t; i < NB; i += 1024)
    if (cnt[i]) base[i] = i * BCAP + atomicAdd(&gcursor[i], cnt[i]);
  __syncthreads();
#pragma unroll
  for (int k = 0; k < 8; ++k) {
    if (bin[k] >= 0) {
      int pos = base[bin[k]] + rnk[k];
      eb1[pos] = make_int2((int)(((u32)cc[k] << 8) | (u32)(rr[k] & 255)),
                           __float_as_int(vv[k]));
    }
  }
}

// ---------------- SpMM1 fused sort+gather+GEMM2; also exports sorted edges ----------------
// s2 = bf16(relu(A@s1+b1) @ W10); writes sorted (col,val) to eb2 and per-row counts.
__global__ __launch_bounds__(1024) void spmm1f_k(const int* __restrict__ gcursor,
                                                 const int2* __restrict__ eb1,
                                                 const u16* __restrict__ s1,
                                                 const float* __restrict__ b1,
                                                 const float* __restrict__ W10,
                                                 u16* __restrict__ s2,
                                                 int2* __restrict__ eb2,
                                                 int* __restrict__ rowcnt) {
  __shared__ int2 se[BCAP];            // 38.9 KB; reused as per-wave h blocks after gather
  __shared__ u16 w10s[64 * W10PAD];    // 6.7 KB bf16 W10 [k][c]
  __shared__ int cnt[BROWS];
  __shared__ int sc[BROWS];
  __shared__ int wsum[4];
  const int bkt = blockIdx.x, t = threadIdx.x;
  const int w = t >> 6, lane = t & 63;
  const int nE = min(gcursor[bkt], BCAP);
  const int beg = bkt * BCAP;
  for (int i = t; i < 64 * W10PAD; i += 1024) {
    int k = i / W10PAD, c = i - k * W10PAD;
    w10s[i] = (c < NC) ? f2bf(W10[k * NC + c]) : (u16)0;
  }
  if (t < BROWS) cnt[t] = 0;
  __syncthreads();
  int2 mye[5]; int myrow[5], myrank[5];
#pragma unroll
  for (int k = 0; k < 5; ++k) {
    int i = t + k * 1024;
    myrow[k] = -1;
    if (i < nE) {
      int2 e = eb1[beg + i];
      mye[k] = e;
      myrow[k] = e.x & 255;
      myrank[k] = atomicAdd(&cnt[myrow[k]], 1);
    }
  }
  __syncthreads();
  int c0 = 0, inc = 0;
  if (t < BROWS) {
    c0 = cnt[t]; inc = c0;
#pragma unroll
    for (int off = 1; off < 64; off <<= 1) {
      int u = __shfl_up(inc, off, 64);
      if ((t & 63) >= off) inc += u;
    }
    if ((t & 63) == 63) wsum[t >> 6] = inc;
  }
  __syncthreads();
  if (t < BROWS) {
    int pre = 0;
#pragma unroll
    for (int k = 0; k < 4; ++k) pre += (k < (t >> 6)) ? wsum[k] : 0;
    sc[t] = pre + inc - c0;
    rowcnt[bkt * BROWS + t] = c0;            // export counts for spmm2
  }
  __syncthreads();
#pragma unroll
  for (int k = 0; k < 5; ++k)
    if (myrow[k] >= 0)
      se[sc[myrow[k]] + myrank[k]] = make_int2((int)((u32)mye[k].x >> 8), mye[k].y);
  __syncthreads();

  // export sorted edges (coalesced) so spmm2 skips the sort
#pragma unroll
  for (int k = 0; k < 5; ++k) {
    int i = t + k * 1024;
    if (i < nE) eb2[beg + i] = se[i];
  }

  // gather: wave w owns rows w*16..w*16+15; h kept in registers
  const float bias = b1[lane];
  float hreg[16];
#pragma unroll 1
  for (int i = 0; i < 16; ++i) {
    int r8 = w * 16 + i;
    int s = sc[r8], n = cnt[r8];
    float a0 = 0.f, a1 = 0.f, a2 = 0.f, a3 = 0.f;
    int j = 0;
    for (; j + 3 < n; j += 4) {
      int2 e0 = se[s + j], e1 = se[s + j + 1], e2 = se[s + j + 2], e3 = se[s + j + 3];
      a0 = fmaf(__int_as_float(e0.y), bf2f(s1[(size_t)e0.x * NH + lane]), a0);
      a1 = fmaf(__int_as_float(e1.y), bf2f(s1[(size_t)e1.x * NH + lane]), a1);
      a2 = fmaf(__int_as_float(e2.y), bf2f(s1[(size_t)e2.x * NH + lane]), a2);
      a3 = fmaf(__int_as_float(e3.y), bf2f(s1[(size_t)e3.x * NH + lane]), a3);
    }
    for (; j < n; ++j) {
      int2 e0 = se[s + j];
      a0 = fmaf(__int_as_float(e0.y), bf2f(s1[(size_t)e0.x * NH + lane]), a0);
    }
    hreg[i] = fmaxf((a0 + a1) + (a2 + a3) + bias, 0.f);
  }
  __syncthreads();   // all waves done reading se -> safe to reuse as h blocks

  u16* hl = (u16*)se + (size_t)w * 16 * HPAD;
#pragma unroll
  for (int i = 0; i < 16; ++i) hl[i * HPAD + lane] = f2bf(hreg[i]);

  const int l15 = lane & 15, l4 = lane >> 4;
  bf16x8 afr[2];
  afr[0] = *(const bf16x8*)&hl[l15 * HPAD + l4 * 8];
  afr[1] = *(const bf16x8*)&hl[l15 * HPAD + 32 + l4 * 8];

  f32x4 acc[3];
#pragma unroll
  for (int ct = 0; ct < 3; ++ct) acc[ct] = (f32x4){0.f, 0.f, 0.f, 0.f};
#pragma unroll
  for (int ct = 0; ct < 3; ++ct) {
#pragma unroll
    for (int kk = 0; kk < 2; ++kk) {
      u16x8 bw;
#pragma unroll
      for (int j = 0; j < 8; ++j)
        bw[j] = w10s[(kk * 32 + l4 * 8 + j) * W10PAD + ct * 16 + l15];
      acc[ct] = __builtin_amdgcn_mfma_f32_16x16x32_bf16(
          afr[kk], __builtin_bit_cast(bf16x8, bw), acc[ct], 0, 0, 0);
    }
  }
#pragma unroll
  for (int ct = 0; ct < 3; ++ct) {
    int c = ct * 16 + l15;
#pragma unroll
    for (int i = 0; i < 4; ++i) {
      int grow = bkt * BROWS + w * 16 + l4 * 4 + i;
      if (c < NC && grow < NND) s2[(size_t)grow * NC + c] = f2bf(acc[ct][i]);
    }
  }
}

// ---------------- SpMM2: pre-sorted edges + b10 + log_softmax (no sort phase) ----------------
__global__ __launch_bounds__(1024) void spmm2s_k(const int* __restrict__ gcursor,
                                                 const int2* __restrict__ eb2,
                                                 const int* __restrict__ rowcnt,
                                                 const u16* __restrict__ s2,
                                                 const float* __restrict__ b10,
                                                 float* __restrict__ out) {
  __shared__ int2 se[BCAP];
  __shared__ int cnt[BROWS];
  __shared__ int sc[BROWS];
  __shared__ int wsum[4];
  const int bkt = blockIdx.x, t = threadIdx.x;
  const int w = t >> 6, lane = t & 63;
  const int nE = min(gcursor[bkt], BCAP);
  const int beg = bkt * BCAP;
  if (t < BROWS) cnt[t] = rowcnt[bkt * BROWS + t];
#pragma unroll
  for (int k = 0; k < 5; ++k) {
    int i = t + k * 1024;
    if (i < nE) se[i] = eb2[beg + i];
  }
  __syncthreads();
  int c0 = 0, inc = 0;
  if (t < BROWS) {
    c0 = cnt[t]; inc = c0;
#pragma unroll
    for (int off = 1; off < 64; off <<= 1) {
      int u = __shfl_up(inc, off, 64);
      if ((t & 63) >= off) inc += u;
    }
    if ((t & 63) == 63) wsum[t >> 6] = inc;
  }
  __syncthreads();
  if (t < BROWS) {
    int pre = 0;
#pragma unroll
    for (int k = 0; k < 4; ++k) pre += (k < (t >> 6)) ? wsum[k] : 0;
    sc[t] = pre + inc - c0;
  }
  __syncthreads();

  const int off0 = (lane < NC) ? lane : 0;
  const float bias = (lane < NC) ? b10[lane] : 0.f;
#pragma unroll 1
  for (int i = 0; i < 16; ++i) {
    int r8 = w * 16 + i;
    int s = sc[r8], n = cnt[r8];
    float a0 = 0.f, a1 = 0.f, a2 = 0.f, a3 = 0.f;
    int j = 0;
    for (; j + 3 < n; j += 4) {
      int2 e0 = se[s + j], e1 = se[s + j + 1], e2 = se[s + j + 2], e3 = se[s + j + 3];
      a0 = fmaf(__int_as_float(e0.y), bf2f(s2[(size_t)e0.x * NC + off0]), a0);
      a1 = fmaf(__int_as_float(e1.y), bf2f(s2[(size_t)e1.x * NC + off0]), a1);
      a2 = fmaf(__int_as_float(e2.y), bf2f(s2[(size_t)e2.x * NC + off0]), a2);
      a3 = fmaf(__int_as_float(e3.y), bf2f(s2[(size_t)e3.x * NC + off0]), a3);
    }
    for (; j < n; ++j) {
      int2 e0 = se[s + j];
      a0 = fmaf(__int_as_float(e0.y), bf2f(s2[(size_t)e0.x * NC + off0]), a0);
    }
    int grow = bkt * BROWS + r8;
    if (grow >= NND) continue;
    float vv = (lane < NC) ? (a0 + a1) + (a2 + a3) + bias : -INFINITY;
    float m = vv;
#pragma unroll
    for (int o = 32; o; o >>= 1) m = fmaxf(m, __shfl_xor(m, o, 64));
    float e = (lane < NC) ? __expf(vv - m) : 0.f;
    float ss = e;
#pragma unroll
    for (int o = 32; o; o >>= 1) ss += __shfl_xor(ss, o, 64);
    if (lane < NC) out[(size_t)grow * NC + lane] = vv - m - __logf(ss);
  }
}

extern "C" void kernel_launch(void* const* d_in, const int* in_sizes, int n_in,
                              void* d_out, int out_size, void* d_ws, size_t ws_size,
                              hipStream_t stream) {
  const float* x    = (const float*)d_in[0];
  const float* adj  = (const float*)d_in[1];
  const float* W1   = (const float*)d_in[2];
  const float* b1   = (const float*)d_in[3];
  const float* W10  = (const float*)d_in[4];
  const float* b10  = (const float*)d_in[5];
  const int*   erow = (const int*)d_in[6];
  const int*   ecol = (const int*)d_in[7];
  float* out = (float*)d_out;

  char* p = (char*)d_ws;
  u16*  s1  = (u16*)p;    p += (size_t)NND * NH * 2;        // 12.8 MB
  u16*  s2  = (u16*)p;    p += (size_t)NND * NC * 2;        // 8 MB
  u16*  w1t = (u16*)p;    p += (size_t)NF * NH * 2;         // 64 KB
  int2* eb1 = (int2*)p;   p += (size_t)NB * BCAP * 8;       // 15.2 MB
  int2* eb2 = (int2*)p;   p += (size_t)NB * BCAP * 8;       // 15.2 MB
  int* rowcnt = (int*)p;  p += (size_t)NB * BROWS * 4;      // 400 KB
  int* gcursor = (int*)p;

  w1t_k<<<(NF * NH + 255) / 256, 256, 0, stream>>>(W1, w1t, gcursor);
  bscatter_k<<<NEB, 1024, 0, stream>>>(adj, erow, ecol, gcursor, eb1);

  gemm1_k<<<(NND + 127) / 128, 256, 0, stream>>>(x, w1t, s1);
  spmm1f_k<<<NB, 1024, 0, stream>>>(gcursor, eb1, s1, b1, W10, s2, eb2, rowcnt);
  spmm2s_k<<<NB, 1024, 0, stream>>>(gcursor, eb2, rowcnt, s2, b10, out);
}